// Round 11
// baseline (2148.098 us; speedup 1.0000x reference)
//
#include <hip/hip_runtime.h>
#include <hip/hip_bf16.h>

// GRU: SEQ=64, BATCH=64, HID=EMB=512, VOCAB=10000, LAYERS=2
// Outputs: logits (64,64,10000) f32 then h_final (2,64,512) f32, concat flat.

#define SEQ 64
#define NPX 16     // worker blocks per XCD
#define NPART 32   // total workers (layer 0 on XCD-A, layer 1 on XCD-B)

typedef short s16x8 __attribute__((ext_vector_type(8)));   // 8 bf16 (4 VGPRs)
typedef float f32x4 __attribute__((ext_vector_type(4)));
typedef int   i32x4 __attribute__((ext_vector_type(4)));
typedef unsigned long long ull;

static __device__ __forceinline__ unsigned short f2bf(float f){
    unsigned int u = __float_as_uint(f);
    return (unsigned short)((u + 0x7FFFu + ((u >> 16) & 1u)) >> 16);  // RNE
}
static __device__ __forceinline__ float bf2f(unsigned short s){
    return __uint_as_float(((unsigned int)s) << 16);
}
static __device__ __forceinline__ float sigm(float x){
    return __fdividef(1.0f, 1.0f + __expf(-x));
}
static __device__ __forceinline__ float tanh_fast(float x){
    float ax = fabsf(x);
    float e = __expf(-2.0f * ax);
    float r = __fdividef(1.0f - e, 1.0f + e);
    return copysignf(r, x);
}
static __device__ __forceinline__ ull pack4bf(const float v[4]){
    union { ull u; unsigned short s[4]; } x;
    x.s[0]=f2bf(v[0]); x.s[1]=f2bf(v[1]); x.s[2]=f2bf(v[2]); x.s[3]=f2bf(v[3]);
    return x.u;
}
// sc0 sc1 = MALL-coherent cross-XCD path (R4/R6/R9-proven). Batched, one wait.
#define SC_LD16_NW(T,A) \
  asm volatile("global_load_dwordx4 %0, %1, off sc0 sc1" : "=&v"(T) : "v"(A) : "memory")
#define SC_WAIT() asm volatile("s_waitcnt vmcnt(0)" ::: "memory")
static __device__ __forceinline__ void sc_st8(void* p, ull v){
    asm volatile("global_store_dwordx2 %0, %1, off sc0 sc1" :: "v"(p), "v"(v) : "memory");
}

// ---------------------------------------------------------------- prep ------
__global__ void prep_kernel(const int* __restrict__ inputs, const float* __restrict__ hidden,
    const float* __restrict__ emb, const float* __restrict__ Wx, const float* __restrict__ Uh,
    const float* __restrict__ Uht, const float* __restrict__ dec_w,
    unsigned short* __restrict__ emb_bf, unsigned short* __restrict__ WxT0,
    unsigned short* __restrict__ UhT0, unsigned short* __restrict__ UhtT0,
    unsigned short* __restrict__ B3T, unsigned short* __restrict__ UhtT1,
    unsigned short* __restrict__ decpad,
    float* __restrict__ HH, unsigned short* __restrict__ HHbf,
    unsigned short* __restrict__ H0m, unsigned int* __restrict__ barzone)
{
    const long long stride = (long long)gridDim.x * blockDim.x;
    const long long t0 = (long long)blockIdx.x * blockDim.x + threadIdx.x;
    for (long long i = t0; i < 4096LL*512; i += stride){
        int r = (int)(i >> 9), k = (int)(i & 511);
        emb_bf[i] = f2bf(emb[(long long)inputs[r]*512 + k]);
    }
    for (long long i = t0; i < 1536LL*512; i += stride){
        int n = (int)(i >> 9), k = (int)(i & 511);
        WxT0[i] = f2bf(Wx[(long long)k*1536 + n]);
    }
    for (long long i = t0; i < 1024LL*512; i += stride){
        int n = (int)(i >> 9), k = (int)(i & 511);
        UhT0[i] = f2bf(Uh[(long long)k*1024 + n]);
    }
    for (long long i = t0; i < 512LL*512; i += stride){
        int n = (int)(i >> 9), k = (int)(i & 511);
        UhtT0[i] = f2bf(Uht[(long long)k*512 + n]);
    }
    for (long long i = t0; i < 1536LL*1024; i += stride){
        int n = (int)(i >> 10), k2 = (int)(i & 1023);
        float v;
        if (k2 < 512) v = Wx[(long long)(512 + k2)*1536 + n];          // Wx[1][k2][n]
        else { int k = k2 - 512; v = (n < 1024) ? Uh[(long long)(512 + k)*1024 + n] : 0.0f; }
        B3T[i] = f2bf(v);
    }
    for (long long i = t0; i < 512LL*512; i += stride){
        int n = (int)(i >> 9), k = (int)(i & 511);
        UhtT1[i] = f2bf(Uht[(long long)(512 + k)*512 + n]);
    }
    for (long long i = t0; i < 10112LL*512; i += stride){
        int n = (int)(i >> 9), k = (int)(i & 511);
        decpad[i] = (n < 10000) ? f2bf(dec_w[(long long)n*512 + k]) : (unsigned short)0;
    }
    for (long long i = t0; i < 65536; i += stride){
        int b = (int)(i >> 10), c = (int)(i & 1023);
        int l = c >> 9, j = c & 511;
        float v = hidden[((long long)l*64 + b)*512 + j];
        HH[i] = v; HHbf[i] = f2bf(v);                                  // HH[b][l*512+j]
    }
    for (long long i = t0; i < 32768; i += stride){
        int b = (int)(i >> 9), j = (int)(i & 511);
        H0m[i] = f2bf(hidden[(long long)b*512 + j]);                   // h0 MALL mirror
    }
    for (long long i = t0; i < 2048; i += stride) barzone[i] = 0u;
}

// ------------------------------------------------- tiled 128x128 bf16 GEMM --
__global__ __launch_bounds__(256) void gemm128(const unsigned short* __restrict__ A,
    const unsigned short* __restrict__ BT, int M, int N, int K, int mode,
    float* __restrict__ outF, unsigned short* __restrict__ outB,
    const float* __restrict__ bias, int Nreal)
{
    __shared__ unsigned short Ash[128*32];
    __shared__ unsigned short Bsh[128*32];
    const int nT = N >> 7;
    const int mb = blockIdx.x / nT, nb = blockIdx.x % nT;
    const int tid = threadIdx.x;
    const int lane = tid & 63, wId = tid >> 6;
    const int wm = wId >> 1, wn = wId & 1;
    const int ln = lane & 15, kg = lane >> 4;
    f32x4 acc[4][4];
    #pragma unroll
    for (int mt = 0; mt < 4; ++mt)
        #pragma unroll
        for (int nt = 0; nt < 4; ++nt) acc[mt][nt] = f32x4{0.f,0.f,0.f,0.f};

    for (int kc = 0; kc < K; kc += 32){
        #pragma unroll
        for (int it = 0; it < 2; ++it){
            int flat = it*256 + tid;
            int row = flat >> 2, kq = flat & 3;
            *(int4*)(&Ash[flat*8]) = *(const int4*)(A + (long long)(mb*128 + row)*K + kc + kq*8);
            *(int4*)(&Bsh[flat*8]) = *(const int4*)(BT + (long long)(nb*128 + row)*K + kc + kq*8);
        }
        __syncthreads();
        s16x8 af[4], bfv[4];
        #pragma unroll
        for (int mt = 0; mt < 4; ++mt) af[mt]  = *(const s16x8*)(&Ash[(wm*64 + mt*16 + ln)*32 + kg*8]);
        #pragma unroll
        for (int nt = 0; nt < 4; ++nt) bfv[nt] = *(const s16x8*)(&Bsh[(wn*64 + nt*16 + ln)*32 + kg*8]);
        #pragma unroll
        for (int mt = 0; mt < 4; ++mt)
            #pragma unroll
            for (int nt = 0; nt < 4; ++nt)
                acc[mt][nt] = __builtin_amdgcn_mfma_f32_16x16x32_bf16(af[mt], bfv[nt], acc[mt][nt], 0, 0, 0);
        __syncthreads();
    }
    #pragma unroll
    for (int mt = 0; mt < 4; ++mt)
        #pragma unroll
        for (int nt = 0; nt < 4; ++nt)
            #pragma unroll
            for (int r = 0; r < 4; ++r){
                int row = mb*128 + wm*64 + mt*16 + kg*4 + r;   // C/D: col=lane&15, row=(lane>>4)*4+reg
                int col = nb*128 + wn*64 + nt*16 + ln;
                float v = acc[mt][nt][r];
                if (mode == 0){
                    outB[(long long)row*N + col] = f2bf(v);
                } else {
                    if (col < Nreal) outF[(long long)row*Nreal + col] = v + bias[col];
                }
            }
}

// -------------------------------------------------------- persistent GRU ----
// Layer 0 on XCD-A, layer 1 on XCD-B (R9-proven structure). Intra-XCD state:
// plain cached ops (vmcnt drain -> L2, buffer_inv -> L1 freshness). Cross-XCD:
// h0 mirror in MALL via sc0sc1. Barrier: per-rank MALL flag lines, bounded
// poll (hang-proof). NEW in R11: idle blocks prefetch next phase-A weight
// streams (B3T on B, WX0-next on A) into local L2 during phase B.
static __device__ __forceinline__ void gsync(unsigned int* flags, int rank, unsigned gen){
    asm volatile("s_waitcnt vmcnt(0)" ::: "memory");   // all stores visible
    __syncthreads();
    if (threadIdx.x < 64){
        if (threadIdx.x == 0){
            asm volatile("global_store_dword %0, %1, off sc0 sc1"
                         :: "v"(flags + rank*32), "v"(gen) : "memory");
        }
        const unsigned int* p = flags + (threadIdx.x & (NPART-1))*32;
        unsigned v; int it = 0;
        do {
            asm volatile("global_load_dword %0, %1, off sc0 sc1\n\ts_waitcnt vmcnt(0)"
                         : "=v"(v) : "v"(p) : "memory");
        } while (__ballot(v >= gen) != ~0ull && ++it < (1 << 20));
    }
    __syncthreads();
    asm volatile("buffer_inv" ::: "memory");           // L1 invalidate (fresh L2 reads)
}

// Wave-tile GEMM: D[16 n][64 b]. A = weight slice (N,K) global (L2-resident),
// B = 4 b-fragments from XOR-swizzled LDS. C/D: col(b)=lane&15, row(n)=(lane>>4)*4+reg.
template<int KIT, int PITCH>
static __device__ __forceinline__ void mmTile(const unsigned short* __restrict__ W,
    const char* __restrict__ lds, int ln, int kg, f32x4 acc[4])
{
    constexpr int K = KIT * 32;
    #pragma unroll
    for (int nt = 0; nt < 4; ++nt) acc[nt] = f32x4{0.f,0.f,0.f,0.f};
    #pragma unroll 4
    for (int k = 0; k < KIT; ++k){
        s16x8 bv[4];
        #pragma unroll
        for (int nt = 0; nt < 4; ++nt){
            const int row = nt*16 + ln;
            bv[nt] = *(const s16x8*)(lds + ((row*PITCH + k*64 + kg*16) ^ ((row & 7) << 4)));
        }
        s16x8 av = *(const s16x8*)(W + ln*K + k*32 + kg*8);
        #pragma unroll
        for (int nt = 0; nt < 4; ++nt)
            acc[nt] = __builtin_amdgcn_mfma_f32_16x16x32_bf16(av, bv[nt], acc[nt], 0, 0, 0);
    }
}

__global__ __launch_bounds__(512, 1) void gru_kernel(
    float* __restrict__ HHf, unsigned short* __restrict__ HHbf,
    const unsigned short* __restrict__ UhT0, const unsigned short* __restrict__ UhtT0,
    const unsigned short* __restrict__ B3T,  const unsigned short* __restrict__ UhtT1,
    const unsigned short* __restrict__ WX0,
    unsigned short* __restrict__ rh0, unsigned short* __restrict__ rh1,
    float* __restrict__ z0, float* __restrict__ z1, float* __restrict__ P3,
    unsigned short* __restrict__ H2bf, unsigned short* __restrict__ H0m,
    const float* __restrict__ b_rzh,
    float* __restrict__ outTail, unsigned int* __restrict__ barzone)
{
    __shared__ __align__(16) char smem[131072];   // 128 KB -> 1 block/CU
    __shared__ int s_rank;
    const int tid = threadIdx.x, lane = tid & 63, wv = tid >> 6;  // 8 waves
    const int ln = lane & 15, kg = lane >> 4;

    // ---- elect 16 workers on each of TWO distinct XCDs (R9-proven) ----
    if (tid == 0){
        unsigned xcc;
        asm volatile("s_getreg_b32 %0, hwreg(HW_REG_XCC_ID)" : "=s"(xcc));
        unsigned my = (xcc & 15u) + 1u;
        int r = -1;
        unsigned a = atomicCAS(barzone + 1, 0u, my);
        if (a == 0u) a = my;
        if (my == a){
            int q = (int)atomicAdd(barzone + 2, 1u);
            if (q < NPX) r = q;                      // XCD-A: ranks 0..15 (layer 0)
        } else {
            unsigned b = atomicCAS(barzone + 3, 0u, my);
            if (b == 0u) b = my;
            if (my == b){
                int q = (int)atomicAdd(barzone + 4, 1u);
                if (q < NPX) r = NPX + q;            // XCD-B: ranks 16..31 (layer 1)
            }
        }
        s_rank = r;
    }
    __syncthreads();
    const int rank = s_rank;
    if (rank < 0) return;                            // non-workers exit

    unsigned int* flags = barzone + 256;
    const bool x0 = (rank < NPX);
    const int lr = rank & 15;                        // local rank in XCD
    const int lw = lr*8 + wv;                        // local wave id 0..127
    const float* b0 = b_rzh;
    const float* b1 = b_rzh + 1536;
    unsigned gen = 0;

    // per-wave bias vectors (clamped addresses keep inactive waves in-bounds)
    const int n0A = lw * 16;                         // phase-A tile base
    const int n0B = (lw < 32 ? lw : 0) * 16;         // phase-B tile base
    const int nA = (n0A < (x0 ? 1024 : 1520)) ? n0A : 0;
    f32x4 biasA = x0 ? *(const f32x4*)(b0 + nA + kg*4)
                     : *(const f32x4*)(b1 + nA + kg*4);
    f32x4 biasB = x0 ? *(const f32x4*)(b0 + 1024 + n0B + kg*4)
                     : *(const f32x4*)(b1 + 1024 + n0B + kg*4);

    for (int ss = 0; ss <= SEQ; ++ss){
        // ===================== phase A: S1(ss)@XCD-A || S3(ss-1)@XCD-B ======
        if (x0){
            if (lr < 8){   // stage h0bf [64][512] local -> LDS pitch 1024, swizzled
                const int4* src = (const int4*)HHbf;
                int4 t[8];
                #pragma unroll
                for (int j = 0; j < 8; ++j){
                    const int c = tid + j*512, b = c >> 6, col = c & 63;
                    t[j] = src[(b << 7) + col];
                }
                #pragma unroll
                for (int j = 0; j < 8; ++j){
                    const int c = tid + j*512, b = c >> 6, col = c & 63;
                    *(int4*)(smem + ((b*1024 + col*16) ^ ((b & 7) << 4))) = t[j];
                }
            }
        } else {
            if (lr < 12){  // stage H [64][1024]: h0 from MALL mirror (sc), h1 local
                i32x4 t0[8]; int4 t1[8];
                const char* srcm = (const char*)H0m;
                const int4* srch = (const int4*)HHbf;
                #pragma unroll
                for (int j = 0; j < 8; ++j){
                    const int c = tid + j*512, b = c >> 6, col = c & 63;
                    SC_LD16_NW(t0[j], srcm + (long long)c*16);
                    t1[j] = srch[(b << 7) + 64 + col];
                }
                SC_WAIT();
                #pragma unroll
                for (int j = 0; j < 8; ++j){
                    const int c = tid + j*512, b = c >> 6, col = c & 63;
                    *(i32x4*)(smem + ((b*2048 + col*16) ^ ((b & 7) << 4))) = t0[j];
                    *(int4*)(smem + ((b*2048 + 1024 + col*16) ^ ((b & 7) << 4))) = t1[j];
                }
            }
        }
        __syncthreads();
        if (x0){
            if (lw < 64 && ss < SEQ){
                // ---- S1 job: n0A of 1024 (uh = h0 @ Uh0), K=512
                const int t = ss;
                const int nq = n0A + kg*4;
                ull wxv[4];
                #pragma unroll
                for (int nt = 0; nt < 4; ++nt)
                    wxv[nt] = *(const ull*)(WX0 + (long long)(t*64 + nt*16 + ln)*1536 + nq);
                f32x4 acc[4];
                mmTile<16,1024>(UhT0 + n0A*512, smem, ln, kg, acc);
                #pragma unroll
                for (int nt = 0; nt < 4; ++nt){
                    const int b = nt*16 + ln;
                    union { ull u; unsigned short s[4]; } wx; wx.u = wxv[nt];
                    float sg[4];
                    #pragma unroll
                    for (int r = 0; r < 4; ++r)
                        sg[r] = sigm(acc[nt][r] + bf2f(wx.s[r]) + biasA[r]);
                    if (nq < 512){
                        union { ull u; unsigned short s[4]; } h;
                        h.u = *(const ull*)(smem + ((b*1024 + nq*2) ^ ((b & 7) << 4)));
                        float rv[4];
                        #pragma unroll
                        for (int r = 0; r < 4; ++r) rv[r] = sg[r] * bf2f(h.s[r]);
                        *(ull*)(rh0 + b*512 + nq) = pack4bf(rv);
                    } else {
                        f32x4 zz = {sg[0], sg[1], sg[2], sg[3]};
                        *(f32x4*)(z0 + b*512 + (nq - 512)) = zz;
                    }
                }
            }
        } else {
            if (lw < 96 && ss >= 1){
                // ---- S3 job: n0A of 1536 ([h0|h1] @ B3T), K=1024
                f32x4 acc[4];
                mmTile<32,2048>(B3T + (long long)n0A*1024, smem, ln, kg, acc);
                const int nq = n0A + kg*4;
                #pragma unroll
                for (int nt = 0; nt < 4; ++nt){
                    const int b = nt*16 + ln;
                    if (nq < 512){
                        union { ull u; unsigned short s[4]; } h;
                        h.u = *(const ull*)(smem + ((b*2048 + (512 + nq)*2) ^ ((b & 7) << 4)));
                        float rv[4];
                        #pragma unroll
                        for (int r = 0; r < 4; ++r)
                            rv[r] = sigm(acc[nt][r] + biasA[r]) * bf2f(h.s[r]);
                        *(ull*)(rh1 + b*512 + nq) = pack4bf(rv);
                    } else if (nq < 1024){
                        float sg[4];
                        #pragma unroll
                        for (int r = 0; r < 4; ++r)
                            sg[r] = sigm(acc[nt][r] + biasA[r]);
                        f32x4 zz = {sg[0], sg[1], sg[2], sg[3]};
                        *(f32x4*)(z1 + b*512 + (nq - 512)) = zz;
                    } else {
                        *(f32x4*)(P3 + b*512 + (nq - 1024)) = acc[nt];
                    }
                }
            }
        }
        ++gen; gsync(flags, rank, gen);

        // ===================== phase B: S2(ss)@XCD-A || S4(ss-1)@XCD-B ======
        if (lr < 4){      // stage rh [64][512] local -> LDS pitch 1024, swizzled
            const int4* src = (const int4*)(x0 ? rh0 : rh1);
            int4 t[8];
            #pragma unroll
            for (int j = 0; j < 8; ++j) t[j] = src[tid + j*512];
            #pragma unroll
            for (int j = 0; j < 8; ++j){
                const int c = tid + j*512;
                *(int4*)(smem + ((c*16) ^ (((c >> 6) & 7) << 4))) = t[j];
            }
        } else {
            // ---- R11: idle blocks prefetch next phase-A weight streams into
            //      the LOCAL XCD L2 (plain cache-allocating loads, XOR-sunk).
            int4 acc4 = {0,0,0,0};
            if (!x0){
                // XCD-B: sweep B3T (3 MB = 196608 int4) across blocks 4..15
                const int4* src = (const int4*)B3T;
                const int base = (lr - 4) * 16384;
                #pragma unroll 8
                for (int j = 0; j < 32; ++j){
                    int4 v = src[base + j*512 + tid];
                    acc4.x ^= v.x; acc4.y ^= v.y; acc4.z ^= v.z; acc4.w ^= v.w;
                }
            } else if (ss + 1 < SEQ){
                // XCD-A: sweep WX0 slice for step ss+1 (192 KB = 12288 int4)
                const int4* src = (const int4*)(WX0 + (long long)(ss + 1)*64*1536);
                const int base = (lr - 4) * 1024;
                #pragma unroll
                for (int j = 0; j < 2; ++j){
                    int4 v = src[base + j*512 + tid];
                    acc4.x ^= v.x; acc4.y ^= v.y; acc4.z ^= v.z; acc4.w ^= v.w;
                }
            }
            asm volatile("" :: "v"(acc4.x), "v"(acc4.y), "v"(acc4.z), "v"(acc4.w));
        }
        __syncthreads();
        if (lw < 32){
            if (x0 && ss < SEQ){
                // ---- S2: h0 update, cols n0B of 512, K=512
                const int t = ss;
                const int nq = n0B + kg*4;
                ull wxv[4]; f32x4 zv[4], hpv[4];
                #pragma unroll
                for (int nt = 0; nt < 4; ++nt){
                    const int b = nt*16 + ln;
                    wxv[nt] = *(const ull*)(WX0 + (long long)(t*64 + b)*1536 + 1024 + nq);
                    zv[nt]  = *(const f32x4*)(z0 + b*512 + nq);
                    hpv[nt] = *(const f32x4*)(HHf + b*1024 + nq);
                }
                f32x4 acc[4];
                mmTile<16,1024>(UhtT0 + n0B*512, smem, ln, kg, acc);
                #pragma unroll
                for (int nt = 0; nt < 4; ++nt){
                    const int b = nt*16 + ln;
                    union { ull u; unsigned short s[4]; } wx; wx.u = wxv[nt];
                    float hn[4];
                    #pragma unroll
                    for (int r = 0; r < 4; ++r){
                        float pre = acc[nt][r] + bf2f(wx.s[r]) + biasB[r];
                        float ht = tanh_fast(pre);
                        hn[r] = (1.0f - zv[nt][r])*hpv[nt][r] + zv[nt][r]*ht;
                    }
                    f32x4 hv = {hn[0], hn[1], hn[2], hn[3]};
                    *(f32x4*)(HHf + b*1024 + nq) = hv;
                    ull pb = pack4bf(hn);
                    *(ull*)(HHbf + b*1024 + nq) = pb;      // local (A consumers)
                    sc_st8(H0m + b*512 + nq, pb);          // mirror (B consumers)
                }
            } else if (!x0 && ss >= 1){
                // ---- S4: h1 update + H2bf, cols n0B of 512, K=512
                const int t = ss - 1;
                const int nq = n0B + kg*4;
                f32x4 ppv[4], zv[4], hpv[4];
                #pragma unroll
                for (int nt = 0; nt < 4; ++nt){
                    const int b = nt*16 + ln;
                    ppv[nt] = *(const f32x4*)(P3 + b*512 + nq);
                    zv[nt]  = *(const f32x4*)(z1 + b*512 + nq);
                    hpv[nt] = *(const f32x4*)(HHf + b*1024 + 512 + nq);
                }
                f32x4 acc[4];
                mmTile<16,1024>(UhtT1 + n0B*512, smem, ln, kg, acc);
                #pragma unroll
                for (int nt = 0; nt < 4; ++nt){
                    const int b = nt*16 + ln;
                    float hn[4];
                    #pragma unroll
                    for (int r = 0; r < 4; ++r){
                        float pre = acc[nt][r] + ppv[nt][r] + biasB[r];
                        float ht = tanh_fast(pre);
                        hn[r] = (1.0f - zv[nt][r])*hpv[nt][r] + zv[nt][r]*ht;
                    }
                    f32x4 hv = {hn[0], hn[1], hn[2], hn[3]};
                    *(f32x4*)(HHf + b*1024 + 512 + nq) = hv;
                    ull pb = pack4bf(hn);
                    *(ull*)(HHbf + b*1024 + 512 + nq) = pb;
                    *(ull*)(H2bf + (long long)(t*64 + b)*512 + nq) = pb;
                }
            }
        }
        ++gen; gsync(flags, rank, gen);
    }

    // h_final tail: each XCD writes its own layer's half (local L2 reads).
    {
        const int base = x0 ? 0 : 512;
        const int obase = x0 ? 0 : 32768;
        for (int c = lr*512 + tid; c < 8192; c += NPX*512){
            const int b = c >> 7, j4 = c & 127;
            f32x4 v = *(const f32x4*)(HHf + b*1024 + base + j4*4);
            *(f32x4*)(outTail + obase + b*512 + j4*4) = v;
        }
    }
}

// ---------------------------------------------------------------- launch ----
extern "C" void kernel_launch(void* const* d_in, const int* in_sizes, int n_in,
                              void* d_out, int out_size, void* d_ws, size_t ws_size,
                              hipStream_t stream)
{
    const int*   inputs = (const int*)d_in[0];
    const float* hidden = (const float*)d_in[1];
    const float* emb    = (const float*)d_in[2];
    const float* Wx     = (const float*)d_in[3];
    const float* Uh     = (const float*)d_in[4];
    const float* Uht    = (const float*)d_in[5];
    const float* b_rzh  = (const float*)d_in[6];
    const float* dec_w  = (const float*)d_in[7];
    const float* dec_b  = (const float*)d_in[8];
    float* out = (float*)d_out;

    char* w = (char*)d_ws;
    size_t off = 0;
    auto alloc = [&](size_t bytes)->char*{
        char* p = w + off; off = (off + bytes + 255) & ~(size_t)255; return p;
    };
    unsigned short* emb_bf = (unsigned short*)alloc(4096LL*512*2);
    unsigned short* WxT0   = (unsigned short*)alloc(1536LL*512*2);
    unsigned short* WX0    = (unsigned short*)alloc(4096LL*1536*2);
    unsigned short* UhT0   = (unsigned short*)alloc(1024LL*512*2);
    unsigned short* UhtT0  = (unsigned short*)alloc(512LL*512*2);
    unsigned short* B3T    = (unsigned short*)alloc(1536LL*1024*2);
    unsigned short* UhtT1  = (unsigned short*)alloc(512LL*512*2);
    unsigned short* decpad = (unsigned short*)alloc(10112LL*512*2);
    float*          HH     = (float*)alloc(65536*4);
    unsigned short* HHbf   = (unsigned short*)alloc(65536*2);
    unsigned short* H0m    = (unsigned short*)alloc(64*512*2);
    unsigned short* rh0    = (unsigned short*)alloc(64*512*2);
    unsigned short* rh1    = (unsigned short*)alloc(64*512*2);
    float*          z0     = (float*)alloc(64*512*4);
    float*          z1     = (float*)alloc(64*512*4);
    float*          P3     = (float*)alloc(64*512*4);
    unsigned short* H2bf   = (unsigned short*)alloc(4096LL*512*2);
    unsigned int*   barzone= (unsigned int*)alloc(8192);
    if (off > ws_size) return;  // workspace too small: fail loudly via absmax

    prep_kernel<<<1024, 256, 0, stream>>>(inputs, hidden, emb, Wx, Uh, Uht, dec_w,
        emb_bf, WxT0, UhT0, UhtT0, B3T, UhtT1, decpad, HH, HHbf, H0m, barzone);

    // WX0 = embed @ Wx0  (M=4096, N=1536, K=512), bf16 out
    gemm128<<<dim3(32*12), 256, 0, stream>>>(emb_bf, WxT0, 4096, 1536, 512,
        0, nullptr, WX0, nullptr, 1536);

    // persistent recurrent kernel: 256 blocks, 16 workers on each of 2 XCDs,
    // idle blocks prefetch weight streams into local L2
    gru_kernel<<<dim3(256), 512, 0, stream>>>(HH, HHbf, UhT0, UhtT0, B3T, UhtT1,
        WX0, rh0, rh1, z0, z1, P3, H2bf, H0m, b_rzh, out + 40960000, barzone);

    // decoder: logits = H2 @ dec_w^T + dec_b  (M=4096, N=10112 padded, K=512)
    gemm128<<<dim3(32*79), 256, 0, stream>>>(H2bf, decpad, 4096, 10112, 512,
        1, out, nullptr, dec_b, 10000);
}

// Round 12
// 2020.380 us; speedup vs baseline: 1.0632x; 1.0632x over previous
//
#include <hip/hip_runtime.h>
#include <hip/hip_bf16.h>

// GRU: SEQ=64, BATCH=64, HID=EMB=512, VOCAB=10000, LAYERS=2
// Outputs: logits (64,64,10000) f32 then h_final (2,64,512) f32, concat flat.

#define SEQ 64
#define NPX 16     // worker blocks per XCD
#define NPART 32   // total workers (layer 0 on XCD-A, layer 1 on XCD-B)

typedef short s16x8 __attribute__((ext_vector_type(8)));   // 8 bf16 (4 VGPRs)
typedef float f32x4 __attribute__((ext_vector_type(4)));
typedef int   i32x4 __attribute__((ext_vector_type(4)));
typedef unsigned long long ull;

static __device__ __forceinline__ unsigned short f2bf(float f){
    unsigned int u = __float_as_uint(f);
    return (unsigned short)((u + 0x7FFFu + ((u >> 16) & 1u)) >> 16);  // RNE
}
static __device__ __forceinline__ float bf2f(unsigned short s){
    return __uint_as_float(((unsigned int)s) << 16);
}
static __device__ __forceinline__ float sigm(float x){
    return __fdividef(1.0f, 1.0f + __expf(-x));
}
static __device__ __forceinline__ float tanh_fast(float x){
    float ax = fabsf(x);
    float e = __expf(-2.0f * ax);
    float r = __fdividef(1.0f - e, 1.0f + e);
    return copysignf(r, x);
}
static __device__ __forceinline__ ull pack4bf(const float v[4]){
    union { ull u; unsigned short s[4]; } x;
    x.s[0]=f2bf(v[0]); x.s[1]=f2bf(v[1]); x.s[2]=f2bf(v[2]); x.s[3]=f2bf(v[3]);
    return x.u;
}
// sc0 sc1 = MALL-coherent cross-XCD path (R4/R6/R9-proven). Batched, one wait.
#define SC_LD16_NW(T,A) \
  asm volatile("global_load_dwordx4 %0, %1, off sc0 sc1" : "=&v"(T) : "v"(A) : "memory")
#define SC_WAIT() asm volatile("s_waitcnt vmcnt(0)" ::: "memory")
static __device__ __forceinline__ void sc_st8(void* p, ull v){
    asm volatile("global_store_dwordx2 %0, %1, off sc0 sc1" :: "v"(p), "v"(v) : "memory");
}

// ---------------------------------------------------------------- prep ------
__global__ void prep_kernel(const int* __restrict__ inputs, const float* __restrict__ hidden,
    const float* __restrict__ emb, const float* __restrict__ Wx, const float* __restrict__ Uh,
    const float* __restrict__ Uht, const float* __restrict__ dec_w,
    unsigned short* __restrict__ emb_bf, unsigned short* __restrict__ WxT0,
    unsigned short* __restrict__ UhT0, unsigned short* __restrict__ UhtT0,
    unsigned short* __restrict__ B3T, unsigned short* __restrict__ UhtT1,
    unsigned short* __restrict__ decpad,
    float* __restrict__ HH, unsigned short* __restrict__ HHbf,
    unsigned short* __restrict__ H0m, unsigned int* __restrict__ barzone)
{
    const long long stride = (long long)gridDim.x * blockDim.x;
    const long long t0 = (long long)blockIdx.x * blockDim.x + threadIdx.x;
    for (long long i = t0; i < 4096LL*512; i += stride){
        int r = (int)(i >> 9), k = (int)(i & 511);
        emb_bf[i] = f2bf(emb[(long long)inputs[r]*512 + k]);
    }
    for (long long i = t0; i < 1536LL*512; i += stride){
        int n = (int)(i >> 9), k = (int)(i & 511);
        WxT0[i] = f2bf(Wx[(long long)k*1536 + n]);
    }
    for (long long i = t0; i < 1024LL*512; i += stride){
        int n = (int)(i >> 9), k = (int)(i & 511);
        UhT0[i] = f2bf(Uh[(long long)k*1024 + n]);
    }
    for (long long i = t0; i < 512LL*512; i += stride){
        int n = (int)(i >> 9), k = (int)(i & 511);
        UhtT0[i] = f2bf(Uht[(long long)k*512 + n]);
    }
    for (long long i = t0; i < 1536LL*1024; i += stride){
        int n = (int)(i >> 10), k2 = (int)(i & 1023);
        float v;
        if (k2 < 512) v = Wx[(long long)(512 + k2)*1536 + n];          // Wx[1][k2][n]
        else { int k = k2 - 512; v = (n < 1024) ? Uh[(long long)(512 + k)*1024 + n] : 0.0f; }
        B3T[i] = f2bf(v);
    }
    for (long long i = t0; i < 512LL*512; i += stride){
        int n = (int)(i >> 9), k = (int)(i & 511);
        UhtT1[i] = f2bf(Uht[(long long)(512 + k)*512 + n]);
    }
    for (long long i = t0; i < 10112LL*512; i += stride){
        int n = (int)(i >> 9), k = (int)(i & 511);
        decpad[i] = (n < 10000) ? f2bf(dec_w[(long long)n*512 + k]) : (unsigned short)0;
    }
    for (long long i = t0; i < 65536; i += stride){
        int b = (int)(i >> 10), c = (int)(i & 1023);
        int l = c >> 9, j = c & 511;
        float v = hidden[((long long)l*64 + b)*512 + j];
        HH[i] = v; HHbf[i] = f2bf(v);                                  // HH[b][l*512+j]
    }
    for (long long i = t0; i < 4LL*32768; i += stride){                // 4-ring h0 mirror
        int idx = (int)(i & 32767);
        int b = idx >> 9, j = idx & 511;
        H0m[i] = f2bf(hidden[(long long)b*512 + j]);
    }
    for (long long i = t0; i < 2048; i += stride) barzone[i] = 0u;
}

// ------------------------------------------------- tiled 128x128 bf16 GEMM --
__global__ __launch_bounds__(256) void gemm128(const unsigned short* __restrict__ A,
    const unsigned short* __restrict__ BT, int M, int N, int K, int mode,
    float* __restrict__ outF, unsigned short* __restrict__ outB,
    const float* __restrict__ bias, int Nreal)
{
    __shared__ unsigned short Ash[128*32];
    __shared__ unsigned short Bsh[128*32];
    const int nT = N >> 7;
    const int mb = blockIdx.x / nT, nb = blockIdx.x % nT;
    const int tid = threadIdx.x;
    const int lane = tid & 63, wId = tid >> 6;
    const int wm = wId >> 1, wn = wId & 1;
    const int ln = lane & 15, kg = lane >> 4;
    f32x4 acc[4][4];
    #pragma unroll
    for (int mt = 0; mt < 4; ++mt)
        #pragma unroll
        for (int nt = 0; nt < 4; ++nt) acc[mt][nt] = f32x4{0.f,0.f,0.f,0.f};

    for (int kc = 0; kc < K; kc += 32){
        #pragma unroll
        for (int it = 0; it < 2; ++it){
            int flat = it*256 + tid;
            int row = flat >> 2, kq = flat & 3;
            *(int4*)(&Ash[flat*8]) = *(const int4*)(A + (long long)(mb*128 + row)*K + kc + kq*8);
            *(int4*)(&Bsh[flat*8]) = *(const int4*)(BT + (long long)(nb*128 + row)*K + kc + kq*8);
        }
        __syncthreads();
        s16x8 af[4], bfv[4];
        #pragma unroll
        for (int mt = 0; mt < 4; ++mt) af[mt]  = *(const s16x8*)(&Ash[(wm*64 + mt*16 + ln)*32 + kg*8]);
        #pragma unroll
        for (int nt = 0; nt < 4; ++nt) bfv[nt] = *(const s16x8*)(&Bsh[(wn*64 + nt*16 + ln)*32 + kg*8]);
        #pragma unroll
        for (int mt = 0; mt < 4; ++mt)
            #pragma unroll
            for (int nt = 0; nt < 4; ++nt)
                acc[mt][nt] = __builtin_amdgcn_mfma_f32_16x16x32_bf16(af[mt], bfv[nt], acc[mt][nt], 0, 0, 0);
        __syncthreads();
    }
    #pragma unroll
    for (int mt = 0; mt < 4; ++mt)
        #pragma unroll
        for (int nt = 0; nt < 4; ++nt)
            #pragma unroll
            for (int r = 0; r < 4; ++r){
                int row = mb*128 + wm*64 + mt*16 + kg*4 + r;   // C/D: col=lane&15, row=(lane>>4)*4+reg
                int col = nb*128 + wn*64 + nt*16 + ln;
                float v = acc[mt][nt][r];
                if (mode == 0){
                    outB[(long long)row*N + col] = f2bf(v);
                } else {
                    if (col < Nreal) outF[(long long)row*Nreal + col] = v + bias[col];
                }
            }
}

// -------------------------------------------------------- persistent GRU ----
// Dependency-scoped barriers (R12):
//  - XCD-A (layer 0) reads NOTHING XCD-B writes -> A never waits for B except
//    a 3-step throttle (H0m is a 4-deep ring, written [ss&3], read [(ss-1)&3]).
//  - bar1 (phase A->B) is intra-XCD on both sides (all edges local).
//  - bar2: B waits for A (H0m readiness) + own XCD; A waits own XCD only.
// Flags in MALL via sc0sc1 (proven). One poller lane per flag. Bounded poll.
static __device__ __forceinline__ void gsync2(unsigned int* flags, int rank, unsigned gen,
                                              int ownBase, int otherBase, int otherGen){
    asm volatile("s_waitcnt vmcnt(0)" ::: "memory");   // all stores visible
    __syncthreads();
    if (threadIdx.x < 64){
        if (threadIdx.x == 0){
            asm volatile("global_store_dword %0, %1, off sc0 sc1"
                         :: "v"(flags + rank*32), "v"(gen) : "memory");
        }
        const int li = threadIdx.x;
        const unsigned int* p = flags;
        unsigned need = 0; bool active = false;
        if (li < NPX){ p = flags + (ownBase + li)*32; need = gen; active = true; }
        else if (li < 2*NPX && otherGen > 0){
            p = flags + (otherBase + (li - NPX))*32; need = (unsigned)otherGen; active = true;
        }
        unsigned v = need; int it = 0;
        do {
            if (active){
                asm volatile("global_load_dword %0, %1, off sc0 sc1\n\ts_waitcnt vmcnt(0)"
                             : "=v"(v) : "v"(p) : "memory");
            }
        } while (__ballot(v >= need) != ~0ull && ++it < (1 << 17));
    }
    __syncthreads();
    asm volatile("buffer_inv" ::: "memory");           // L1 invalidate (fresh L2 reads)
}

// Wave-tile GEMM: D[16 n][64 b]. A = weight slice, row stride WSTRIDE elems
// (L2-resident), B = 4 b-fragments from XOR-swizzled LDS (PITCH bytes/row).
// C/D: col(b)=lane&15, row(n)=(lane>>4)*4+reg.
template<int KIT, int PITCH, int WSTRIDE>
static __device__ __forceinline__ void mmTile(const unsigned short* __restrict__ W,
    const char* __restrict__ lds, int ln, int kg, f32x4 acc[4])
{
    #pragma unroll
    for (int nt = 0; nt < 4; ++nt) acc[nt] = f32x4{0.f,0.f,0.f,0.f};
    #pragma unroll 4
    for (int k = 0; k < KIT; ++k){
        s16x8 bv[4];
        #pragma unroll
        for (int nt = 0; nt < 4; ++nt){
            const int row = nt*16 + ln;
            bv[nt] = *(const s16x8*)(lds + ((row*PITCH + k*64 + kg*16) ^ ((row & 7) << 4)));
        }
        s16x8 av = *(const s16x8*)(W + ln*WSTRIDE + k*32 + kg*8);
        #pragma unroll
        for (int nt = 0; nt < 4; ++nt)
            acc[nt] = __builtin_amdgcn_mfma_f32_16x16x32_bf16(av, bv[nt], acc[nt], 0, 0, 0);
    }
}

__global__ __launch_bounds__(512, 1) void gru_kernel(
    float* __restrict__ HHf, unsigned short* __restrict__ HHbf,
    const unsigned short* __restrict__ UhT0, const unsigned short* __restrict__ UhtT0,
    const unsigned short* __restrict__ B3T,  const unsigned short* __restrict__ UhtT1,
    const unsigned short* __restrict__ WX0,
    unsigned short* __restrict__ rh0, unsigned short* __restrict__ rh1,
    float* __restrict__ z0, float* __restrict__ z1, float* __restrict__ P3,
    unsigned short* __restrict__ H2bf, unsigned short* __restrict__ H0m,
    const float* __restrict__ b_rzh,
    float* __restrict__ outTail, unsigned int* __restrict__ barzone)
{
    __shared__ __align__(16) char smem[131072];   // 128 KB -> 1 block/CU
    __shared__ int s_rank;
    const int tid = threadIdx.x, lane = tid & 63, wv = tid >> 6;  // 8 waves
    const int ln = lane & 15, kg = lane >> 4;

    // ---- elect 16 workers on each of TWO distinct XCDs (R9-proven) ----
    if (tid == 0){
        unsigned xcc;
        asm volatile("s_getreg_b32 %0, hwreg(HW_REG_XCC_ID)" : "=s"(xcc));
        unsigned my = (xcc & 15u) + 1u;
        int r = -1;
        unsigned a = atomicCAS(barzone + 1, 0u, my);
        if (a == 0u) a = my;
        if (my == a){
            int q = (int)atomicAdd(barzone + 2, 1u);
            if (q < NPX) r = q;                      // XCD-A: ranks 0..15 (layer 0)
        } else {
            unsigned b = atomicCAS(barzone + 3, 0u, my);
            if (b == 0u) b = my;
            if (my == b){
                int q = (int)atomicAdd(barzone + 4, 1u);
                if (q < NPX) r = NPX + q;            // XCD-B: ranks 16..31 (layer 1)
            }
        }
        s_rank = r;
    }
    __syncthreads();
    const int rank = s_rank;
    if (rank < 0) return;                            // non-workers exit

    unsigned int* flags = barzone + 256;
    const bool x0 = (rank < NPX);
    const int lr = rank & 15;                        // local rank in XCD
    const int lw = lr*8 + wv;                        // local wave id 0..127
    const float* b0 = b_rzh;
    const float* b1 = b_rzh + 1536;
    unsigned gen = 0;

    // per-wave bias vectors (clamped addresses keep inactive waves in-bounds)
    const int n0A = lw * 16;                         // phase-A tile base
    const int n0B = (lw < 32 ? lw : 0) * 16;         // phase-B tile base
    const int nA = (n0A < (x0 ? 1024 : 1520)) ? n0A : 0;
    f32x4 biasA = x0 ? *(const f32x4*)(b0 + nA + kg*4)
                     : *(const f32x4*)(b1 + nA + kg*4);
    f32x4 biasB = x0 ? *(const f32x4*)(b0 + 1024 + n0B + kg*4)
                     : *(const f32x4*)(b1 + 1024 + n0B + kg*4);

    for (int ss = 0; ss <= SEQ; ++ss){
        // ===================== phase A: S1(ss)@XCD-A || S3(ss-1)@XCD-B ======
        if (x0){
            if (lr < 8){   // stage h0bf [64][512] local -> LDS pitch 1024, swizzled
                const int4* src = (const int4*)HHbf;
                int4 t[8];
                #pragma unroll
                for (int j = 0; j < 8; ++j){
                    const int c = tid + j*512, b = c >> 6, col = c & 63;
                    t[j] = src[(b << 7) + col];
                }
                #pragma unroll
                for (int j = 0; j < 8; ++j){
                    const int c = tid + j*512, b = c >> 6, col = c & 63;
                    *(int4*)(smem + ((b*1024 + col*16) ^ ((b & 7) << 4))) = t[j];
                }
            }
        } else {
            if (lr < 12){  // stage H [64][1024]: h0 from ring mirror (sc), h1 local
                i32x4 t0[8]; int4 t1[8];
                const char* srcm = (const char*)(H0m + (long long)((ss + 3) & 3)*32768);
                const int4* srch = (const int4*)HHbf;
                #pragma unroll
                for (int j = 0; j < 8; ++j){
                    const int c = tid + j*512, b = c >> 6, col = c & 63;
                    SC_LD16_NW(t0[j], srcm + (long long)c*16);
                    t1[j] = srch[(b << 7) + 64 + col];
                }
                SC_WAIT();
                #pragma unroll
                for (int j = 0; j < 8; ++j){
                    const int c = tid + j*512, b = c >> 6, col = c & 63;
                    *(i32x4*)(smem + ((b*2048 + col*16) ^ ((b & 7) << 4))) = t0[j];
                    *(int4*)(smem + ((b*2048 + 1024 + col*16) ^ ((b & 7) << 4))) = t1[j];
                }
            }
        }
        __syncthreads();
        if (x0){
            if (lw < 64 && ss < SEQ){
                // ---- S1 job: n0A of 1024 (uh = h0 @ Uh0), K=512
                const int t = ss;
                const int nq = n0A + kg*4;
                ull wxv[4];
                #pragma unroll
                for (int nt = 0; nt < 4; ++nt)
                    wxv[nt] = *(const ull*)(WX0 + (long long)(t*64 + nt*16 + ln)*1536 + nq);
                f32x4 acc[4];
                mmTile<16,1024,512>(UhT0 + n0A*512, smem, ln, kg, acc);
                #pragma unroll
                for (int nt = 0; nt < 4; ++nt){
                    const int b = nt*16 + ln;
                    union { ull u; unsigned short s[4]; } wx; wx.u = wxv[nt];
                    float sg[4];
                    #pragma unroll
                    for (int r = 0; r < 4; ++r)
                        sg[r] = sigm(acc[nt][r] + bf2f(wx.s[r]) + biasA[r]);
                    if (nq < 512){
                        union { ull u; unsigned short s[4]; } h;
                        h.u = *(const ull*)(smem + ((b*1024 + nq*2) ^ ((b & 7) << 4)));
                        float rv[4];
                        #pragma unroll
                        for (int r = 0; r < 4; ++r) rv[r] = sg[r] * bf2f(h.s[r]);
                        *(ull*)(rh0 + b*512 + nq) = pack4bf(rv);
                    } else {
                        f32x4 zz = {sg[0], sg[1], sg[2], sg[3]};
                        *(f32x4*)(z0 + b*512 + (nq - 512)) = zz;
                    }
                }
            }
        } else {
            if (lw < 96 && ss >= 1){
                // ---- S3 job: n0A of 1536 ([h0|h1] @ B3T)
                //      n0A <1024: K=1024; n0A >=1024: Uh-half is zero -> K=512
                f32x4 acc[4];
                if (lw < 64) mmTile<32,2048,1024>(B3T + (long long)n0A*1024, smem, ln, kg, acc);
                else         mmTile<16,2048,1024>(B3T + (long long)n0A*1024, smem, ln, kg, acc);
                const int nq = n0A + kg*4;
                #pragma unroll
                for (int nt = 0; nt < 4; ++nt){
                    const int b = nt*16 + ln;
                    if (nq < 512){
                        union { ull u; unsigned short s[4]; } h;
                        h.u = *(const ull*)(smem + ((b*2048 + (512 + nq)*2) ^ ((b & 7) << 4)));
                        float rv[4];
                        #pragma unroll
                        for (int r = 0; r < 4; ++r)
                            rv[r] = sigm(acc[nt][r] + biasA[r]) * bf2f(h.s[r]);
                        *(ull*)(rh1 + b*512 + nq) = pack4bf(rv);
                    } else if (nq < 1024){
                        float sg[4];
                        #pragma unroll
                        for (int r = 0; r < 4; ++r)
                            sg[r] = sigm(acc[nt][r] + biasA[r]);
                        f32x4 zz = {sg[0], sg[1], sg[2], sg[3]};
                        *(f32x4*)(z1 + b*512 + (nq - 512)) = zz;
                    } else {
                        *(f32x4*)(P3 + b*512 + (nq - 1024)) = acc[nt];
                    }
                }
            }
        }
        ++gen;   // bar1: intra-XCD; A additionally throttles to <=3 steps ahead of B
        if (x0) gsync2(flags, rank, gen, 0,  16, (int)gen - 6);
        else    gsync2(flags, rank, gen, 16, 0,  0);

        // ===================== phase B: S2(ss)@XCD-A || S4(ss-1)@XCD-B ======
        if (lr < 4){      // stage rh [64][512] local -> LDS pitch 1024, swizzled
            const int4* src = (const int4*)(x0 ? rh0 : rh1);
            int4 t[8];
            #pragma unroll
            for (int j = 0; j < 8; ++j) t[j] = src[tid + j*512];
            #pragma unroll
            for (int j = 0; j < 8; ++j){
                const int c = tid + j*512;
                *(int4*)(smem + ((c*16) ^ (((c >> 6) & 7) << 4))) = t[j];
            }
        }
        __syncthreads();
        if (lw < 32){
            if (x0 && ss < SEQ){
                // ---- S2: h0 update, cols n0B of 512, K=512
                const int t = ss;
                const int nq = n0B + kg*4;
                ull wxv[4]; f32x4 zv[4], hpv[4];
                #pragma unroll
                for (int nt = 0; nt < 4; ++nt){
                    const int b = nt*16 + ln;
                    wxv[nt] = *(const ull*)(WX0 + (long long)(t*64 + b)*1536 + 1024 + nq);
                    zv[nt]  = *(const f32x4*)(z0 + b*512 + nq);
                    hpv[nt] = *(const f32x4*)(HHf + b*1024 + nq);
                }
                f32x4 acc[4];
                mmTile<16,1024,512>(UhtT0 + n0B*512, smem, ln, kg, acc);
                unsigned short* H0w = H0m + (long long)(ss & 3)*32768;   // ring slot
                #pragma unroll
                for (int nt = 0; nt < 4; ++nt){
                    const int b = nt*16 + ln;
                    union { ull u; unsigned short s[4]; } wx; wx.u = wxv[nt];
                    float hn[4];
                    #pragma unroll
                    for (int r = 0; r < 4; ++r){
                        float pre = acc[nt][r] + bf2f(wx.s[r]) + biasB[r];
                        float ht = tanh_fast(pre);
                        hn[r] = (1.0f - zv[nt][r])*hpv[nt][r] + zv[nt][r]*ht;
                    }
                    f32x4 hv = {hn[0], hn[1], hn[2], hn[3]};
                    *(f32x4*)(HHf + b*1024 + nq) = hv;
                    ull pb = pack4bf(hn);
                    *(ull*)(HHbf + b*1024 + nq) = pb;      // local (A consumers)
                    sc_st8(H0w + b*512 + nq, pb);          // ring mirror (B consumers)
                }
            } else if (!x0 && ss >= 1){
                // ---- S4: h1 update + H2bf, cols n0B of 512, K=512
                const int t = ss - 1;
                const int nq = n0B + kg*4;
                f32x4 ppv[4], zv[4], hpv[4];
                #pragma unroll
                for (int nt = 0; nt < 4; ++nt){
                    const int b = nt*16 + ln;
                    ppv[nt] = *(const f32x4*)(P3 + b*512 + nq);
                    zv[nt]  = *(const f32x4*)(z1 + b*512 + nq);
                    hpv[nt] = *(const f32x4*)(HHf + b*1024 + 512 + nq);
                }
                f32x4 acc[4];
                mmTile<16,1024,512>(UhtT1 + n0B*512, smem, ln, kg, acc);
                #pragma unroll
                for (int nt = 0; nt < 4; ++nt){
                    const int b = nt*16 + ln;
                    float hn[4];
                    #pragma unroll
                    for (int r = 0; r < 4; ++r){
                        float pre = acc[nt][r] + ppv[nt][r] + biasB[r];
                        float ht = tanh_fast(pre);
                        hn[r] = (1.0f - zv[nt][r])*hpv[nt][r] + zv[nt][r]*ht;
                    }
                    f32x4 hv = {hn[0], hn[1], hn[2], hn[3]};
                    *(f32x4*)(HHf + b*1024 + 512 + nq) = hv;
                    ull pb = pack4bf(hn);
                    *(ull*)(HHbf + b*1024 + 512 + nq) = pb;
                    *(ull*)(H2bf + (long long)(t*64 + b)*512 + nq) = pb;
                }
            }
        }
        ++gen;   // bar2: A waits own XCD only; B waits own XCD + A (H0m ready)
        if (x0) gsync2(flags, rank, gen, 0,  16, 0);
        else    gsync2(flags, rank, gen, 16, 0,  (int)gen);
    }

    // h_final tail: each XCD writes its own layer's half (local L2 reads).
    {
        const int base = x0 ? 0 : 512;
        const int obase = x0 ? 0 : 32768;
        for (int c = lr*512 + tid; c < 8192; c += NPX*512){
            const int b = c >> 7, j4 = c & 127;
            f32x4 v = *(const f32x4*)(HHf + b*1024 + base + j4*4);
            *(f32x4*)(outTail + obase + b*512 + j4*4) = v;
        }
    }
}

// ---------------------------------------------------------------- launch ----
extern "C" void kernel_launch(void* const* d_in, const int* in_sizes, int n_in,
                              void* d_out, int out_size, void* d_ws, size_t ws_size,
                              hipStream_t stream)
{
    const int*   inputs = (const int*)d_in[0];
    const float* hidden = (const float*)d_in[1];
    const float* emb    = (const float*)d_in[2];
    const float* Wx     = (const float*)d_in[3];
    const float* Uh     = (const float*)d_in[4];
    const float* Uht    = (const float*)d_in[5];
    const float* b_rzh  = (const float*)d_in[6];
    const float* dec_w  = (const float*)d_in[7];
    const float* dec_b  = (const float*)d_in[8];
    float* out = (float*)d_out;

    char* w = (char*)d_ws;
    size_t off = 0;
    auto alloc = [&](size_t bytes)->char*{
        char* p = w + off; off = (off + bytes + 255) & ~(size_t)255; return p;
    };
    unsigned short* emb_bf = (unsigned short*)alloc(4096LL*512*2);
    unsigned short* WxT0   = (unsigned short*)alloc(1536LL*512*2);
    unsigned short* WX0    = (unsigned short*)alloc(4096LL*1536*2);
    unsigned short* UhT0   = (unsigned short*)alloc(1024LL*512*2);
    unsigned short* UhtT0  = (unsigned short*)alloc(512LL*512*2);
    unsigned short* B3T    = (unsigned short*)alloc(1536LL*1024*2);
    unsigned short* UhtT1  = (unsigned short*)alloc(512LL*512*2);
    unsigned short* decpad = (unsigned short*)alloc(10112LL*512*2);
    float*          HH     = (float*)alloc(65536*4);
    unsigned short* HHbf   = (unsigned short*)alloc(65536*2);
    unsigned short* H0m    = (unsigned short*)alloc(4LL*32768*2);   // 4-ring mirror
    unsigned short* rh0    = (unsigned short*)alloc(64*512*2);
    unsigned short* rh1    = (unsigned short*)alloc(64*512*2);
    float*          z0     = (float*)alloc(64*512*4);
    float*          z1     = (float*)alloc(64*512*4);
    float*          P3     = (float*)alloc(64*512*4);
    unsigned short* H2bf   = (unsigned short*)alloc(4096LL*512*2);
    unsigned int*   barzone= (unsigned int*)alloc(8192);
    if (off > ws_size) return;  // workspace too small: fail loudly via absmax

    prep_kernel<<<1024, 256, 0, stream>>>(inputs, hidden, emb, Wx, Uh, Uht, dec_w,
        emb_bf, WxT0, UhT0, UhtT0, B3T, UhtT1, decpad, HH, HHbf, H0m, barzone);

    // WX0 = embed @ Wx0  (M=4096, N=1536, K=512), bf16 out
    gemm128<<<dim3(32*12), 256, 0, stream>>>(emb_bf, WxT0, 4096, 1536, 512,
        0, nullptr, WX0, nullptr, 1536);

    // persistent recurrent kernel: 2 XCDs, dependency-scoped barriers,
    // layer-0 free-run with 4-deep H0m ring
    gru_kernel<<<dim3(256), 512, 0, stream>>>(HH, HHbf, UhT0, UhtT0, B3T, UhtT1,
        WX0, rh0, rh1, z0, z1, P3, H2bf, H0m, b_rzh, out + 40960000, barzone);

    // decoder: logits = H2 @ dec_w^T + dec_b  (M=4096, N=10112 padded, K=512)
    gemm128<<<dim3(32*79), 256, 0, stream>>>(H2bf, decpad, 4096, 10112, 512,
        1, out, nullptr, dec_b, 10000);
}

// Round 13
// 1784.222 us; speedup vs baseline: 1.2039x; 1.1324x over previous
//
#include <hip/hip_runtime.h>
#include <hip/hip_bf16.h>

// GRU: SEQ=64, BATCH=64, HID=EMB=512, VOCAB=10000, LAYERS=2
// Outputs: logits (64,64,10000) f32 then h_final (2,64,512) f32, concat flat.
// R13: batch-split — 4 groups x 16 batch rows, one XCD each, both layers
// group-local. No cross-XCD data. 8-block group barriers (MALL flags, proven).

#define SEQ 64
#define NGROUPS 4
#define BPG 8      // blocks per group (one XCD)

typedef short s16x8 __attribute__((ext_vector_type(8)));   // 8 bf16 (4 VGPRs)
typedef float f32x4 __attribute__((ext_vector_type(4)));
typedef unsigned long long ull;

static __device__ __forceinline__ unsigned short f2bf(float f){
    unsigned int u = __float_as_uint(f);
    return (unsigned short)((u + 0x7FFFu + ((u >> 16) & 1u)) >> 16);  // RNE
}
static __device__ __forceinline__ float bf2f(unsigned short s){
    return __uint_as_float(((unsigned int)s) << 16);
}
static __device__ __forceinline__ float sigm(float x){
    return __fdividef(1.0f, 1.0f + __expf(-x));
}
static __device__ __forceinline__ float tanh_fast(float x){
    float ax = fabsf(x);
    float e = __expf(-2.0f * ax);
    float r = __fdividef(1.0f - e, 1.0f + e);
    return copysignf(r, x);
}
static __device__ __forceinline__ ull pack4bf(const float v[4]){
    union { ull u; unsigned short s[4]; } x;
    x.s[0]=f2bf(v[0]); x.s[1]=f2bf(v[1]); x.s[2]=f2bf(v[2]); x.s[3]=f2bf(v[3]);
    return x.u;
}

// ---------------------------------------------------------------- prep ------
__global__ void prep_kernel(const int* __restrict__ inputs, const float* __restrict__ hidden,
    const float* __restrict__ emb, const float* __restrict__ Wx, const float* __restrict__ Uh,
    const float* __restrict__ Uht, const float* __restrict__ dec_w,
    unsigned short* __restrict__ emb_bf, unsigned short* __restrict__ WxT0,
    unsigned short* __restrict__ UhT0, unsigned short* __restrict__ UhtT0,
    unsigned short* __restrict__ B3T, unsigned short* __restrict__ UhtT1,
    unsigned short* __restrict__ decpad,
    float* __restrict__ HH, unsigned short* __restrict__ HHbf,
    unsigned int* __restrict__ barzone)
{
    const long long stride = (long long)gridDim.x * blockDim.x;
    const long long t0 = (long long)blockIdx.x * blockDim.x + threadIdx.x;
    for (long long i = t0; i < 4096LL*512; i += stride){
        int r = (int)(i >> 9), k = (int)(i & 511);
        emb_bf[i] = f2bf(emb[(long long)inputs[r]*512 + k]);
    }
    for (long long i = t0; i < 1536LL*512; i += stride){
        int n = (int)(i >> 9), k = (int)(i & 511);
        WxT0[i] = f2bf(Wx[(long long)k*1536 + n]);
    }
    for (long long i = t0; i < 1024LL*512; i += stride){
        int n = (int)(i >> 9), k = (int)(i & 511);
        UhT0[i] = f2bf(Uh[(long long)k*1024 + n]);
    }
    for (long long i = t0; i < 512LL*512; i += stride){
        int n = (int)(i >> 9), k = (int)(i & 511);
        UhtT0[i] = f2bf(Uht[(long long)k*512 + n]);
    }
    for (long long i = t0; i < 1536LL*1024; i += stride){
        int n = (int)(i >> 10), k2 = (int)(i & 1023);
        float v;
        if (k2 < 512) v = Wx[(long long)(512 + k2)*1536 + n];          // Wx[1][k2][n]
        else { int k = k2 - 512; v = (n < 1024) ? Uh[(long long)(512 + k)*1024 + n] : 0.0f; }
        B3T[i] = f2bf(v);
    }
    for (long long i = t0; i < 512LL*512; i += stride){
        int n = (int)(i >> 9), k = (int)(i & 511);
        UhtT1[i] = f2bf(Uht[(long long)(512 + k)*512 + n]);
    }
    for (long long i = t0; i < 10112LL*512; i += stride){
        int n = (int)(i >> 9), k = (int)(i & 511);
        decpad[i] = (n < 10000) ? f2bf(dec_w[(long long)n*512 + k]) : (unsigned short)0;
    }
    for (long long i = t0; i < 65536; i += stride){
        int b = (int)(i >> 10), c = (int)(i & 1023);
        int l = c >> 9, j = c & 511;
        float v = hidden[((long long)l*64 + b)*512 + j];
        HH[i] = v; HHbf[i] = f2bf(v);                                  // HH[b][l*512+j]
    }
    for (long long i = t0; i < 2048; i += stride) barzone[i] = 0u;
}

// ------------------------------------------------- tiled 128x128 bf16 GEMM --
__global__ __launch_bounds__(256) void gemm128(const unsigned short* __restrict__ A,
    const unsigned short* __restrict__ BT, int M, int N, int K, int mode,
    float* __restrict__ outF, unsigned short* __restrict__ outB,
    const float* __restrict__ bias, int Nreal)
{
    __shared__ unsigned short Ash[128*32];
    __shared__ unsigned short Bsh[128*32];
    const int nT = N >> 7;
    const int mb = blockIdx.x / nT, nb = blockIdx.x % nT;
    const int tid = threadIdx.x;
    const int lane = tid & 63, wId = tid >> 6;
    const int wm = wId >> 1, wn = wId & 1;
    const int ln = lane & 15, kg = lane >> 4;
    f32x4 acc[4][4];
    #pragma unroll
    for (int mt = 0; mt < 4; ++mt)
        #pragma unroll
        for (int nt = 0; nt < 4; ++nt) acc[mt][nt] = f32x4{0.f,0.f,0.f,0.f};

    for (int kc = 0; kc < K; kc += 32){
        #pragma unroll
        for (int it = 0; it < 2; ++it){
            int flat = it*256 + tid;
            int row = flat >> 2, kq = flat & 3;
            *(int4*)(&Ash[flat*8]) = *(const int4*)(A + (long long)(mb*128 + row)*K + kc + kq*8);
            *(int4*)(&Bsh[flat*8]) = *(const int4*)(BT + (long long)(nb*128 + row)*K + kc + kq*8);
        }
        __syncthreads();
        s16x8 af[4], bfv[4];
        #pragma unroll
        for (int mt = 0; mt < 4; ++mt) af[mt]  = *(const s16x8*)(&Ash[(wm*64 + mt*16 + ln)*32 + kg*8]);
        #pragma unroll
        for (int nt = 0; nt < 4; ++nt) bfv[nt] = *(const s16x8*)(&Bsh[(wn*64 + nt*16 + ln)*32 + kg*8]);
        #pragma unroll
        for (int mt = 0; mt < 4; ++mt)
            #pragma unroll
            for (int nt = 0; nt < 4; ++nt)
                acc[mt][nt] = __builtin_amdgcn_mfma_f32_16x16x32_bf16(af[mt], bfv[nt], acc[mt][nt], 0, 0, 0);
        __syncthreads();
    }
    #pragma unroll
    for (int mt = 0; mt < 4; ++mt)
        #pragma unroll
        for (int nt = 0; nt < 4; ++nt)
            #pragma unroll
            for (int r = 0; r < 4; ++r){
                int row = mb*128 + wm*64 + mt*16 + kg*4 + r;   // C/D: col=lane&15, row=(lane>>4)*4+reg
                int col = nb*128 + wn*64 + nt*16 + ln;
                float v = acc[mt][nt][r];
                if (mode == 0){
                    outB[(long long)row*N + col] = f2bf(v);
                } else {
                    if (col < Nreal) outF[(long long)row*Nreal + col] = v + bias[col];
                }
            }
}

// -------------------------------------------------------- persistent GRU ----
// Group-local barrier: 8 flag lines in MALL (sc0sc1, R6/R7/R9-proven).
// One poller lane per flag; bounded (hang-proof). buffer_inv after -> plain
// cached loads see fresh XCD-L2 data (R7-proven).
static __device__ __forceinline__ void gsyncg(unsigned int* gf, int lrank, unsigned gen){
    asm volatile("s_waitcnt vmcnt(0)" ::: "memory");   // plain stores -> L2 visible
    __syncthreads();
    if (threadIdx.x < 64){
        if (threadIdx.x == 0){
            asm volatile("global_store_dword %0, %1, off sc0 sc1"
                         :: "v"(gf + lrank*32), "v"(gen) : "memory");
        }
        const unsigned int* p = gf + (threadIdx.x & (BPG-1))*32;
        unsigned v = gen; int it = 0;
        do {
            if (threadIdx.x < BPG){
                asm volatile("global_load_dword %0, %1, off sc0 sc1\n\ts_waitcnt vmcnt(0)"
                             : "=v"(v) : "v"(p) : "memory");
            }
        } while (__ballot(v >= gen) != ~0ull && ++it < (1 << 20));
    }
    __syncthreads();
    asm volatile("buffer_inv" ::: "memory");           // L1 invalidate
}

// M=16 wave-tile: D[16 n][16 b]. av = weight row n0+ln (stride WSTRIDE elems,
// XCD-L2 cached); bv = h fragment from XOR-swizzled LDS row ln (PITCH bytes).
// C/D: col(b)=lane&15, row(n)=(lane>>4)*4+reg.
template<int KIT, int PITCH, int WSTRIDE>
static __device__ __forceinline__ f32x4 mmT16(const unsigned short* __restrict__ W,
    const char* __restrict__ lds, int ln, int kg)
{
    f32x4 acc = {0.f, 0.f, 0.f, 0.f};
    #pragma unroll 4
    for (int k = 0; k < KIT; ++k){
        s16x8 bv = *(const s16x8*)(lds + ((ln*PITCH + k*64 + kg*16) ^ ((ln & 7) << 4)));
        s16x8 av = *(const s16x8*)(W + ln*WSTRIDE + k*32 + kg*8);
        acc = __builtin_amdgcn_mfma_f32_16x16x32_bf16(av, bv, acc, 0, 0, 0);
    }
    return acc;
}

__global__ __launch_bounds__(512, 1) void gru_kernel(
    float* __restrict__ HHf, unsigned short* __restrict__ HHbf,
    const unsigned short* __restrict__ UhT0, const unsigned short* __restrict__ UhtT0,
    const unsigned short* __restrict__ B3T,  const unsigned short* __restrict__ UhtT1,
    const unsigned short* __restrict__ WX0,
    unsigned short* __restrict__ rh0, unsigned short* __restrict__ rh1,
    float* __restrict__ z0, float* __restrict__ z1, float* __restrict__ P3,
    unsigned short* __restrict__ H2bf, const float* __restrict__ b_rzh,
    float* __restrict__ outTail, unsigned int* __restrict__ barzone)
{
    __shared__ __align__(16) char smem[32768];    // 16 rows x 2048 B
    __shared__ int s_grp, s_lrank;
    const int tid = threadIdx.x, lane = tid & 63, wv = tid >> 6;  // 8 waves
    const int ln = lane & 15, kg = lane >> 4;

    // ---- elect 8 blocks on each of 4 distinct XCDs (extends R9 scheme) ----
    if (tid == 0){
        unsigned xcc;
        asm volatile("s_getreg_b32 %0, hwreg(HW_REG_XCC_ID)" : "=s"(xcc));
        xcc &= 15u;
        int lrk = (int)atomicAdd(barzone + 8 + xcc, 1u);
        int g = -1;
        if (lrk == 0){
            unsigned gi = atomicAdd(barzone + 1, 1u);
            __hip_atomic_store(barzone + 40 + xcc, gi + 1u,
                               __ATOMIC_RELEASE, __HIP_MEMORY_SCOPE_AGENT);
            g = (int)gi;
        } else if (lrk < BPG){
            unsigned v = 0; int it = 0;
            do { v = __hip_atomic_load(barzone + 40 + xcc,
                                       __ATOMIC_ACQUIRE, __HIP_MEMORY_SCOPE_AGENT);
            } while (v == 0u && ++it < (1 << 22));
            g = v ? (int)v - 1 : -1;
        }
        if (g >= NGROUPS) g = -1;
        s_grp = g; s_lrank = lrk;
    }
    __syncthreads();
    const int grp = s_grp, lrank = s_lrank;
    if (grp < 0 || lrank >= BPG) return;         // non-workers exit

    unsigned int* gf = barzone + 256 + grp*256;  // 8 flag lines per group
    const int g16 = grp * 16;                    // group's batch base
    const int lw = lrank*8 + wv;                 // group wave id 0..63
    const float* b0 = b_rzh;
    const float* b1 = b_rzh + 1536;
    unsigned gen = 0;

    for (int ss = 0; ss <= SEQ; ++ss){
        // ========== phase A: stage h0|h1 (16 rows x 2048B, swizzled) =======
        {
            const int4* src = (const int4*)HHbf;       // group rows, local L2
            int4 t[4];
            #pragma unroll
            for (int j = 0; j < 4; ++j){
                const int c = tid + j*512, row = c >> 7, col = c & 127;
                t[j] = src[(g16 + row)*128 + col];
            }
            #pragma unroll
            for (int j = 0; j < 4; ++j){
                const int c = tid + j*512, row = c >> 7, col = c & 127;
                *(int4*)(smem + ((row*2048 + col*16) ^ ((row & 7) << 4))) = t[j];
            }
        }
        __syncthreads();
        // ---- S1(ss): all 64 waves, tile n0 = lw*16 of 1024, K=512 (h0)
        if (ss < SEQ){
            const int n0 = lw*16, nq = n0 + kg*4;
            const int b = g16 + ln;
            union { ull u; unsigned short s[4]; } wx;
            wx.u = *(const ull*)(WX0 + (long long)(ss*64 + b)*1536 + nq);
            f32x4 acc = mmT16<16,2048,512>(UhT0 + n0*512, smem, ln, kg);
            f32x4 bias = *(const f32x4*)(b0 + nq);
            float sg[4];
            #pragma unroll
            for (int r = 0; r < 4; ++r)
                sg[r] = sigm(acc[r] + bf2f(wx.s[r]) + bias[r]);
            if (nq < 512){
                union { ull u; unsigned short s[4]; } h;
                h.u = *(const ull*)(smem + ((ln*2048 + nq*2) ^ ((ln & 7) << 4)));
                float rv[4];
                #pragma unroll
                for (int r = 0; r < 4; ++r) rv[r] = sg[r] * bf2f(h.s[r]);
                *(ull*)(rh0 + b*512 + nq) = pack4bf(rv);
            } else {
                f32x4 zz = {sg[0], sg[1], sg[2], sg[3]};
                *(f32x4*)(z0 + b*512 + (nq - 512)) = zz;
            }
        }
        // ---- S3(ss-1): tile lw of [0,1024) K=1024; waves<32 also tile
        //      1024+lw*16 (Uh-half zero -> K=512, h0 only)
        if (ss >= 1){
            const int n0 = lw*16, nq = n0 + kg*4;
            const int b = g16 + ln;
            f32x4 acc = mmT16<32,2048,1024>(B3T + (long long)n0*1024, smem, ln, kg);
            f32x4 bias = *(const f32x4*)(b1 + nq);
            if (nq < 512){
                union { ull u; unsigned short s[4]; } h;
                h.u = *(const ull*)(smem + ((ln*2048 + 1024 + nq*2) ^ ((ln & 7) << 4)));
                float rv[4];
                #pragma unroll
                for (int r = 0; r < 4; ++r)
                    rv[r] = sigm(acc[r] + bias[r]) * bf2f(h.s[r]);
                *(ull*)(rh1 + b*512 + nq) = pack4bf(rv);
            } else {
                float sg[4];
                #pragma unroll
                for (int r = 0; r < 4; ++r)
                    sg[r] = sigm(acc[r] + bias[r]);
                f32x4 zz = {sg[0], sg[1], sg[2], sg[3]};
                *(f32x4*)(z1 + b*512 + (nq - 512)) = zz;
            }
            if (lw < 32){
                const int n0b = 1024 + lw*16, nqb = n0b + kg*4;
                f32x4 acc2 = mmT16<16,2048,1024>(B3T + (long long)n0b*1024, smem, ln, kg);
                *(f32x4*)(P3 + b*512 + (nqb - 1024)) = acc2;   // bias added in S4
            }
        }
        ++gen; gsyncg(gf, lrank, gen);

        // ========== phase B: stage rh0 (base 0) + rh1 (base 16384) =========
        {
            const int4* s0 = (const int4*)rh0;
            const int4* s1p = (const int4*)rh1;
            int4 t[4];
            #pragma unroll
            for (int j = 0; j < 2; ++j){
                const int c = tid + j*512, row = c >> 6, col = c & 63;
                t[j]     = s0[(g16 + row)*64 + col];
                t[j + 2] = s1p[(g16 + row)*64 + col];
            }
            #pragma unroll
            for (int j = 0; j < 2; ++j){
                const int c = tid + j*512, row = c >> 6, col = c & 63;
                const int off = (row*1024 + col*16) ^ ((row & 7) << 4);
                *(int4*)(smem + off) = t[j];
                *(int4*)(smem + 16384 + off) = t[j + 2];
            }
        }
        __syncthreads();
        if (lw < 32){
            if (ss < SEQ){
                // ---- S2(ss): h0 update, tile n0 = lw*16 of 512
                const int n0 = lw*16, nq = n0 + kg*4;
                const int b = g16 + ln;
                union { ull u; unsigned short s[4]; } wx;
                wx.u = *(const ull*)(WX0 + (long long)(ss*64 + b)*1536 + 1024 + nq);
                f32x4 zv  = *(const f32x4*)(z0 + b*512 + nq);
                f32x4 hpv = *(const f32x4*)(HHf + b*1024 + nq);
                f32x4 acc = mmT16<16,1024,512>(UhtT0 + n0*512, smem, ln, kg);
                f32x4 bias = *(const f32x4*)(b0 + 1024 + nq);
                float hn[4];
                #pragma unroll
                for (int r = 0; r < 4; ++r){
                    float pre = acc[r] + bf2f(wx.s[r]) + bias[r];
                    float ht = tanh_fast(pre);
                    hn[r] = (1.0f - zv[r])*hpv[r] + zv[r]*ht;
                }
                f32x4 hv = {hn[0], hn[1], hn[2], hn[3]};
                *(f32x4*)(HHf + b*1024 + nq) = hv;
                *(ull*)(HHbf + b*1024 + nq) = pack4bf(hn);
            }
        } else {
            if (ss >= 1){
                // ---- S4(ss-1): h1 update + H2bf, tile n0 = (lw-32)*16
                const int t = ss - 1;
                const int n0 = (lw - 32)*16, nq = n0 + kg*4;
                const int b = g16 + ln;
                f32x4 ppv = *(const f32x4*)(P3 + b*512 + nq);
                f32x4 zv  = *(const f32x4*)(z1 + b*512 + nq);
                f32x4 hpv = *(const f32x4*)(HHf + b*1024 + 512 + nq);
                f32x4 acc = mmT16<16,1024,512>(UhtT1 + n0*512, smem + 16384, ln, kg);
                f32x4 bias = *(const f32x4*)(b1 + 1024 + nq);
                float hn[4];
                #pragma unroll
                for (int r = 0; r < 4; ++r){
                    float pre = acc[r] + ppv[r] + bias[r];
                    float ht = tanh_fast(pre);
                    hn[r] = (1.0f - zv[r])*hpv[r] + zv[r]*ht;
                }
                f32x4 hv = {hn[0], hn[1], hn[2], hn[3]};
                *(f32x4*)(HHf + b*1024 + 512 + nq) = hv;
                ull pb = pack4bf(hn);
                *(ull*)(HHbf + b*1024 + 512 + nq) = pb;
                *(ull*)(H2bf + (long long)(t*64 + b)*512 + nq) = pb;
            }
        }
        ++gen; gsyncg(gf, lrank, gen);
    }

    // h_final tail: group writes its 16 rows x 2 layers (local L2 reads).
    {
        const int c = lrank*512 + tid;           // 0..4095, exactly one f32x4
        const int lb = c >> 8, rest = c & 255;
        const int l = rest >> 7, j4 = rest & 127;
        const int b = g16 + lb;
        f32x4 v = *(const f32x4*)(HHf + b*1024 + l*512 + j4*4);
        *(f32x4*)(outTail + l*32768 + b*512 + j4*4) = v;
    }
}

// ---------------------------------------------------------------- launch ----
extern "C" void kernel_launch(void* const* d_in, const int* in_sizes, int n_in,
                              void* d_out, int out_size, void* d_ws, size_t ws_size,
                              hipStream_t stream)
{
    const int*   inputs = (const int*)d_in[0];
    const float* hidden = (const float*)d_in[1];
    const float* emb    = (const float*)d_in[2];
    const float* Wx     = (const float*)d_in[3];
    const float* Uh     = (const float*)d_in[4];
    const float* Uht    = (const float*)d_in[5];
    const float* b_rzh  = (const float*)d_in[6];
    const float* dec_w  = (const float*)d_in[7];
    const float* dec_b  = (const float*)d_in[8];
    float* out = (float*)d_out;

    char* w = (char*)d_ws;
    size_t off = 0;
    auto alloc = [&](size_t bytes)->char*{
        char* p = w + off; off = (off + bytes + 255) & ~(size_t)255; return p;
    };
    unsigned short* emb_bf = (unsigned short*)alloc(4096LL*512*2);
    unsigned short* WxT0   = (unsigned short*)alloc(1536LL*512*2);
    unsigned short* WX0    = (unsigned short*)alloc(4096LL*1536*2);
    unsigned short* UhT0   = (unsigned short*)alloc(1024LL*512*2);
    unsigned short* UhtT0  = (unsigned short*)alloc(512LL*512*2);
    unsigned short* B3T    = (unsigned short*)alloc(1536LL*1024*2);
    unsigned short* UhtT1  = (unsigned short*)alloc(512LL*512*2);
    unsigned short* decpad = (unsigned short*)alloc(10112LL*512*2);
    float*          HH     = (float*)alloc(65536*4);
    unsigned short* HHbf   = (unsigned short*)alloc(65536*2);
    unsigned short* rh0    = (unsigned short*)alloc(64*512*2);
    unsigned short* rh1    = (unsigned short*)alloc(64*512*2);
    float*          z0     = (float*)alloc(64*512*4);
    float*          z1     = (float*)alloc(64*512*4);
    float*          P3     = (float*)alloc(64*512*4);
    unsigned short* H2bf   = (unsigned short*)alloc(4096LL*512*2);
    unsigned int*   barzone= (unsigned int*)alloc(8192);
    if (off > ws_size) return;  // workspace too small: fail loudly via absmax

    prep_kernel<<<1024, 256, 0, stream>>>(inputs, hidden, emb, Wx, Uh, Uht, dec_w,
        emb_bf, WxT0, UhT0, UhtT0, B3T, UhtT1, decpad, HH, HHbf, barzone);

    // WX0 = embed @ Wx0  (M=4096, N=1536, K=512), bf16 out
    gemm128<<<dim3(32*12), 256, 0, stream>>>(emb_bf, WxT0, 4096, 1536, 512,
        0, nullptr, WX0, nullptr, 1536);

    // persistent recurrent kernel: 4 batch-groups x 8 blocks, one XCD each,
    // both layers group-local, group barriers only
    gru_kernel<<<dim3(256), 512, 0, stream>>>(HH, HHbf, UhT0, UhtT0, B3T, UhtT1,
        WX0, rh0, rh1, z0, z1, P3, H2bf, b_rzh, out + 40960000, barzone);

    // decoder: logits = H2 @ dec_w^T + dec_b  (M=4096, N=10112 padded, K=512)
    gemm128<<<dim3(32*79), 256, 0, stream>>>(H2bf, decpad, 4096, 10112, 512,
        1, out, nullptr, dec_b, 10000);
}

// Round 14
// 1421.086 us; speedup vs baseline: 1.5116x; 1.2555x over previous
//
#include <hip/hip_runtime.h>
#include <hip/hip_bf16.h>

// GRU: SEQ=64, BATCH=64, HID=EMB=512, VOCAB=10000, LAYERS=2
// Outputs: logits (64,64,10000) f32 then h_final (2,64,512) f32, concat flat.
// R14: 4 pairs of XCDs. Pair g: XCD 2g = layer 0 of batch rows [16g,16g+16)
// (weights 1.5MB, L2-resident); XCD 2g+1 = layer 1 (3MB, L2-resident).
// Cross edge per pair: h0 mirror via MALL sc0sc1 (R9-proven). Pair barriers.

#define SEQ 64
#define BPX 8      // worker blocks per XCD

typedef short s16x8 __attribute__((ext_vector_type(8)));   // 8 bf16 (4 VGPRs)
typedef float f32x4 __attribute__((ext_vector_type(4)));
typedef int   i32x4 __attribute__((ext_vector_type(4)));
typedef unsigned long long ull;

static __device__ __forceinline__ unsigned short f2bf(float f){
    unsigned int u = __float_as_uint(f);
    return (unsigned short)((u + 0x7FFFu + ((u >> 16) & 1u)) >> 16);  // RNE
}
static __device__ __forceinline__ float bf2f(unsigned short s){
    return __uint_as_float(((unsigned int)s) << 16);
}
static __device__ __forceinline__ float sigm(float x){
    return __fdividef(1.0f, 1.0f + __expf(-x));
}
static __device__ __forceinline__ float tanh_fast(float x){
    float ax = fabsf(x);
    float e = __expf(-2.0f * ax);
    float r = __fdividef(1.0f - e, 1.0f + e);
    return copysignf(r, x);
}
static __device__ __forceinline__ ull pack4bf(const float v[4]){
    union { ull u; unsigned short s[4]; } x;
    x.s[0]=f2bf(v[0]); x.s[1]=f2bf(v[1]); x.s[2]=f2bf(v[2]); x.s[3]=f2bf(v[3]);
    return x.u;
}
// sc0 sc1 = MALL-coherent cross-XCD path (R4/R6/R9-proven). Batched, one wait.
#define SC_LD16_NW(T,A) \
  asm volatile("global_load_dwordx4 %0, %1, off sc0 sc1" : "=&v"(T) : "v"(A) : "memory")
#define SC_WAIT() asm volatile("s_waitcnt vmcnt(0)" ::: "memory")
static __device__ __forceinline__ void sc_st8(void* p, ull v){
    asm volatile("global_store_dwordx2 %0, %1, off sc0 sc1" :: "v"(p), "v"(v) : "memory");
}

// ---------------------------------------------------------------- prep ------
__global__ void prep_kernel(const int* __restrict__ inputs, const float* __restrict__ hidden,
    const float* __restrict__ emb, const float* __restrict__ Wx, const float* __restrict__ Uh,
    const float* __restrict__ Uht, const float* __restrict__ dec_w,
    unsigned short* __restrict__ emb_bf, unsigned short* __restrict__ WxT0,
    unsigned short* __restrict__ UhT0, unsigned short* __restrict__ UhtT0,
    unsigned short* __restrict__ Wx1T, unsigned short* __restrict__ Uh1T,
    unsigned short* __restrict__ UhtT1, unsigned short* __restrict__ decpad,
    float* __restrict__ HH, unsigned short* __restrict__ HHbf,
    unsigned short* __restrict__ H0m, unsigned int* __restrict__ barzone)
{
    const long long stride = (long long)gridDim.x * blockDim.x;
    const long long t0 = (long long)blockIdx.x * blockDim.x + threadIdx.x;
    for (long long i = t0; i < 4096LL*512; i += stride){
        int r = (int)(i >> 9), k = (int)(i & 511);
        emb_bf[i] = f2bf(emb[(long long)inputs[r]*512 + k]);
    }
    for (long long i = t0; i < 1536LL*512; i += stride){
        int n = (int)(i >> 9), k = (int)(i & 511);
        WxT0[i] = f2bf(Wx[(long long)k*1536 + n]);
    }
    for (long long i = t0; i < 1024LL*512; i += stride){
        int n = (int)(i >> 9), k = (int)(i & 511);
        UhT0[i] = f2bf(Uh[(long long)k*1024 + n]);
    }
    for (long long i = t0; i < 512LL*512; i += stride){
        int n = (int)(i >> 9), k = (int)(i & 511);
        UhtT0[i] = f2bf(Uht[(long long)k*512 + n]);
    }
    for (long long i = t0; i < 1536LL*512; i += stride){
        int n = (int)(i >> 9), k = (int)(i & 511);
        Wx1T[i] = f2bf(Wx[(long long)(512 + k)*1536 + n]);     // Wx[1][k][n]
    }
    for (long long i = t0; i < 1024LL*512; i += stride){
        int n = (int)(i >> 9), k = (int)(i & 511);
        Uh1T[i] = f2bf(Uh[(long long)(512 + k)*1024 + n]);     // Uh[1][k][n]
    }
    for (long long i = t0; i < 512LL*512; i += stride){
        int n = (int)(i >> 9), k = (int)(i & 511);
        UhtT1[i] = f2bf(Uht[(long long)(512 + k)*512 + n]);
    }
    for (long long i = t0; i < 10112LL*512; i += stride){
        int n = (int)(i >> 9), k = (int)(i & 511);
        decpad[i] = (n < 10000) ? f2bf(dec_w[(long long)n*512 + k]) : (unsigned short)0;
    }
    for (long long i = t0; i < 65536; i += stride){
        int b = (int)(i >> 10), c = (int)(i & 1023);
        int l = c >> 9, j = c & 511;
        float v = hidden[((long long)l*64 + b)*512 + j];
        HH[i] = v; HHbf[i] = f2bf(v);                          // HH[b][l*512+j]
    }
    for (long long i = t0; i < 32768; i += stride){
        int b = (int)(i >> 9), j = (int)(i & 511);
        H0m[i] = f2bf(hidden[(long long)b*512 + j]);           // h0 MALL mirror
    }
    for (long long i = t0; i < 4096; i += stride) barzone[i] = 0u;
}

// ------------------------------------------------- tiled 128x128 bf16 GEMM --
__global__ __launch_bounds__(256) void gemm128(const unsigned short* __restrict__ A,
    const unsigned short* __restrict__ BT, int M, int N, int K, int mode,
    float* __restrict__ outF, unsigned short* __restrict__ outB,
    const float* __restrict__ bias, int Nreal)
{
    __shared__ unsigned short Ash[128*32];
    __shared__ unsigned short Bsh[128*32];
    const int nT = N >> 7;
    const int mb = blockIdx.x / nT, nb = blockIdx.x % nT;
    const int tid = threadIdx.x;
    const int lane = tid & 63, wId = tid >> 6;
    const int wm = wId >> 1, wn = wId & 1;
    const int ln = lane & 15, kg = lane >> 4;
    f32x4 acc[4][4];
    #pragma unroll
    for (int mt = 0; mt < 4; ++mt)
        #pragma unroll
        for (int nt = 0; nt < 4; ++nt) acc[mt][nt] = f32x4{0.f,0.f,0.f,0.f};

    for (int kc = 0; kc < K; kc += 32){
        #pragma unroll
        for (int it = 0; it < 2; ++it){
            int flat = it*256 + tid;
            int row = flat >> 2, kq = flat & 3;
            *(int4*)(&Ash[flat*8]) = *(const int4*)(A + (long long)(mb*128 + row)*K + kc + kq*8);
            *(int4*)(&Bsh[flat*8]) = *(const int4*)(BT + (long long)(nb*128 + row)*K + kc + kq*8);
        }
        __syncthreads();
        s16x8 af[4], bfv[4];
        #pragma unroll
        for (int mt = 0; mt < 4; ++mt) af[mt]  = *(const s16x8*)(&Ash[(wm*64 + mt*16 + ln)*32 + kg*8]);
        #pragma unroll
        for (int nt = 0; nt < 4; ++nt) bfv[nt] = *(const s16x8*)(&Bsh[(wn*64 + nt*16 + ln)*32 + kg*8]);
        #pragma unroll
        for (int mt = 0; mt < 4; ++mt)
            #pragma unroll
            for (int nt = 0; nt < 4; ++nt)
                acc[mt][nt] = __builtin_amdgcn_mfma_f32_16x16x32_bf16(af[mt], bfv[nt], acc[mt][nt], 0, 0, 0);
        __syncthreads();
    }
    #pragma unroll
    for (int mt = 0; mt < 4; ++mt)
        #pragma unroll
        for (int nt = 0; nt < 4; ++nt)
            #pragma unroll
            for (int r = 0; r < 4; ++r){
                int row = mb*128 + wm*64 + mt*16 + kg*4 + r;   // C/D: col=lane&15, row=(lane>>4)*4+reg
                int col = nb*128 + wn*64 + nt*16 + ln;
                float v = acc[mt][nt][r];
                if (mode == 0){
                    outB[(long long)row*N + col] = f2bf(v);
                } else {
                    if (col < Nreal) outF[(long long)row*Nreal + col] = v + bias[col];
                }
            }
}

// -------------------------------------------------------- persistent GRU ----
// Pair barrier: 16 flag lines in MALL (sc0sc1, proven). One poller lane per
// flag; bounded. buffer_inv -> plain cached loads see fresh local L2 (R7).
static __device__ __forceinline__ void gsyncp(unsigned int* flags, int fidx, int pbase,
                                              unsigned gen){
    SC_WAIT();
    __syncthreads();
    if (threadIdx.x < 64){
        if (threadIdx.x == 0){
            asm volatile("global_store_dword %0, %1, off sc0 sc1"
                         :: "v"(flags + fidx*32), "v"(gen) : "memory");
        }
        const unsigned int* p = flags + (pbase + (threadIdx.x & 15))*32;
        unsigned v = gen; int it = 0;
        do {
            if (threadIdx.x < 16){
                asm volatile("global_load_dword %0, %1, off sc0 sc1\n\ts_waitcnt vmcnt(0)"
                             : "=v"(v) : "v"(p) : "memory");
            }
        } while (__ballot(v >= gen) != ~0ull && ++it < (1 << 20));
    }
    __syncthreads();
    asm volatile("buffer_inv" ::: "memory");
}

// M=16 wave-tile with accumulate-in: D[16 n][16 b]. av = weight row (stride
// WSTRIDE elems, local-L2 cached); bv = LDS fragment (PITCH bytes/row, XOR swz).
// C/D: col(b)=lane&15, row(n)=(lane>>4)*4+reg.
template<int KIT, int PITCH, int WSTRIDE>
static __device__ __forceinline__ f32x4 mmT16(const unsigned short* __restrict__ W,
    const char* __restrict__ lds, int ln, int kg, f32x4 acc)
{
    #pragma unroll 4
    for (int k = 0; k < KIT; ++k){
        s16x8 bv = *(const s16x8*)(lds + ((ln*PITCH + k*64 + kg*16) ^ ((ln & 7) << 4)));
        s16x8 av = *(const s16x8*)(W + ln*WSTRIDE + k*32 + kg*8);
        acc = __builtin_amdgcn_mfma_f32_16x16x32_bf16(av, bv, acc, 0, 0, 0);
    }
    return acc;
}

__global__ __launch_bounds__(512, 1) void gru_kernel(
    float* __restrict__ HHf, unsigned short* __restrict__ HHbf,
    const unsigned short* __restrict__ UhT0, const unsigned short* __restrict__ UhtT0,
    const unsigned short* __restrict__ Wx1T, const unsigned short* __restrict__ Uh1T,
    const unsigned short* __restrict__ UhtT1,
    const unsigned short* __restrict__ WX0,
    unsigned short* __restrict__ rh0, unsigned short* __restrict__ rh1,
    float* __restrict__ z0, float* __restrict__ z1, float* __restrict__ P3,
    unsigned short* __restrict__ H2bf, unsigned short* __restrict__ H0m,
    const float* __restrict__ b_rzh,
    float* __restrict__ outTail, unsigned int* __restrict__ barzone)
{
    __shared__ __align__(16) char smem[32768];    // 16 rows x 2048 B
    __shared__ int s_xcc, s_lrank;
    const int tid = threadIdx.x, lane = tid & 63, wv = tid >> 6;  // 8 waves
    const int ln = lane & 15, kg = lane >> 4;

    // ---- direct XCD mapping: XCC_ID 0..7 (m09-verified); 8 workers each ----
    if (tid == 0){
        unsigned xcc;
        asm volatile("s_getreg_b32 %0, hwreg(HW_REG_XCC_ID)" : "=s"(xcc));
        xcc &= 7u;
        s_xcc = (int)xcc;
        s_lrank = (int)atomicAdd(barzone + 8 + xcc, 1u);
    }
    __syncthreads();
    const int lrank = s_lrank;
    if (lrank >= BPX) return;                    // spare blocks exit
    const int xcc = s_xcc;
    const int grp = xcc >> 1;                    // pair id 0..3
    const bool L0 = (xcc & 1) == 0;              // even XCD: layer 0
    const int g16 = grp * 16;                    // batch base
    const int lw = lrank*8 + wv;                 // XCD wave id 0..63
    const int fidx = xcc*8 + lrank;              // global flag index
    const int pbase = grp*16;                    // pair's flag base
    unsigned int* flags = barzone + 256;
    const float* b0 = b_rzh;
    const float* b1 = b_rzh + 1536;
    const f32x4 zero = {0.f, 0.f, 0.f, 0.f};
    unsigned gen = 0;

    for (int ss = 0; ss <= SEQ; ++ss){
        // ========== phase A: S1(ss)@L0-XCD || S3(ss-1)@L1-XCD ==============
        if (L0){
            // stage h0 (16 rows x 1024B, pitch 1024, swizzled), local
            const int4* src = (const int4*)HHbf;
            int4 t[2];
            #pragma unroll
            for (int j = 0; j < 2; ++j){
                const int c = tid + j*512, row = c >> 6, col = c & 63;
                t[j] = src[(g16 + row)*128 + col];
            }
            #pragma unroll
            for (int j = 0; j < 2; ++j){
                const int c = tid + j*512, row = c >> 6, col = c & 63;
                *(int4*)(smem + ((row*1024 + col*16) ^ ((row & 7) << 4))) = t[j];
            }
        } else {
            // stage h0 (mirror, sc) | h1 (local) -> 16 rows x 2048B pitch
            i32x4 tm[2]; int4 tl[2];
            const char* srcm = (const char*)H0m;
            const int4* srch = (const int4*)HHbf;
            #pragma unroll
            for (int j = 0; j < 2; ++j){
                const int c = tid + j*512, row = c >> 6, col = c & 63;
                SC_LD16_NW(tm[j], srcm + ((long long)(g16 + row)*64 + col)*16);
                tl[j] = srch[(g16 + row)*128 + 64 + col];
            }
            SC_WAIT();
            #pragma unroll
            for (int j = 0; j < 2; ++j){
                const int c = tid + j*512, row = c >> 6, col = c & 63;
                *(i32x4*)(smem + ((row*2048 + col*16) ^ ((row & 7) << 4))) = tm[j];
                *(int4*)(smem + ((row*2048 + 1024 + col*16) ^ ((row & 7) << 4))) = tl[j];
            }
        }
        __syncthreads();
        if (L0){
            if (ss < SEQ){
                // ---- S1: tile n0 = lw*16 of 1024, K=512
                const int n0 = lw*16, nq = n0 + kg*4;
                const int b = g16 + ln;
                union { ull u; unsigned short s[4]; } wx;
                wx.u = *(const ull*)(WX0 + (long long)(ss*64 + b)*1536 + nq);
                f32x4 acc = mmT16<16,1024,512>(UhT0 + n0*512, smem, ln, kg, zero);
                f32x4 bias = *(const f32x4*)(b0 + nq);
                float sg[4];
                #pragma unroll
                for (int r = 0; r < 4; ++r)
                    sg[r] = sigm(acc[r] + bf2f(wx.s[r]) + bias[r]);
                if (nq < 512){
                    union { ull u; unsigned short s[4]; } h;
                    h.u = *(const ull*)(smem + ((ln*1024 + nq*2) ^ ((ln & 7) << 4)));
                    float rv[4];
                    #pragma unroll
                    for (int r = 0; r < 4; ++r) rv[r] = sg[r] * bf2f(h.s[r]);
                    *(ull*)(rh0 + b*512 + nq) = pack4bf(rv);
                } else {
                    f32x4 zz = {sg[0], sg[1], sg[2], sg[3]};
                    *(f32x4*)(z0 + b*512 + (nq - 512)) = zz;
                }
            }
        } else {
            if (ss >= 1){
                // ---- S3: tile n0 = lw*16 of [0,1024): Wx1T(h0) + Uh1T(h1)
                const int n0 = lw*16, nq = n0 + kg*4;
                const int b = g16 + ln;
                f32x4 acc = mmT16<16,2048,512>(Wx1T + n0*512, smem, ln, kg, zero);
                acc = mmT16<16,2048,512>(Uh1T + n0*512, smem + 1024, ln, kg, acc);
                f32x4 bias = *(const f32x4*)(b1 + nq);
                if (nq < 512){
                    union { ull u; unsigned short s[4]; } h;
                    h.u = *(const ull*)(smem + ((ln*2048 + 1024 + nq*2) ^ ((ln & 7) << 4)));
                    float rv[4];
                    #pragma unroll
                    for (int r = 0; r < 4; ++r)
                        rv[r] = sigm(acc[r] + bias[r]) * bf2f(h.s[r]);
                    *(ull*)(rh1 + b*512 + nq) = pack4bf(rv);
                } else {
                    float sg[4];
                    #pragma unroll
                    for (int r = 0; r < 4; ++r)
                        sg[r] = sigm(acc[r] + bias[r]);
                    f32x4 zz = {sg[0], sg[1], sg[2], sg[3]};
                    *(f32x4*)(z1 + b*512 + (nq - 512)) = zz;
                }
                if (lw < 32){
                    // P3 tile: n0b in [1024,1536), h0 only (Uh half is zero)
                    const int n0b = 1024 + lw*16, nqb = n0b + kg*4;
                    f32x4 acc2 = mmT16<16,2048,512>(Wx1T + (long long)n0b*512, smem, ln, kg, zero);
                    *(f32x4*)(P3 + b*512 + (nqb - 1024)) = acc2;   // bias in S4
                }
            }
        }
        ++gen; gsyncp(flags, fidx, pbase, gen);

        // ========== phase B: S2(ss)@L0-XCD || S4(ss-1)@L1-XCD ==============
        {
            // stage rh (16 rows x 1024B, pitch 1024, swizzled), local
            const int4* src = (const int4*)(L0 ? rh0 : rh1);
            int4 t[2];
            #pragma unroll
            for (int j = 0; j < 2; ++j){
                const int c = tid + j*512, row = c >> 6, col = c & 63;
                t[j] = src[(g16 + row)*64 + col];
            }
            #pragma unroll
            for (int j = 0; j < 2; ++j){
                const int c = tid + j*512, row = c >> 6, col = c & 63;
                *(int4*)(smem + ((row*1024 + col*16) ^ ((row & 7) << 4))) = t[j];
            }
        }
        __syncthreads();
        if (lw < 32){
            if (L0 && ss < SEQ){
                // ---- S2: h0 update, tile n0 = lw*16 of 512
                const int n0 = lw*16, nq = n0 + kg*4;
                const int b = g16 + ln;
                union { ull u; unsigned short s[4]; } wx;
                wx.u = *(const ull*)(WX0 + (long long)(ss*64 + b)*1536 + 1024 + nq);
                f32x4 zv  = *(const f32x4*)(z0 + b*512 + nq);
                f32x4 hpv = *(const f32x4*)(HHf + b*1024 + nq);
                f32x4 acc = mmT16<16,1024,512>(UhtT0 + n0*512, smem, ln, kg, zero);
                f32x4 bias = *(const f32x4*)(b0 + 1024 + nq);
                float hn[4];
                #pragma unroll
                for (int r = 0; r < 4; ++r){
                    float pre = acc[r] + bf2f(wx.s[r]) + bias[r];
                    float ht = tanh_fast(pre);
                    hn[r] = (1.0f - zv[r])*hpv[r] + zv[r]*ht;
                }
                f32x4 hv = {hn[0], hn[1], hn[2], hn[3]};
                *(f32x4*)(HHf + b*1024 + nq) = hv;
                ull pb = pack4bf(hn);
                *(ull*)(HHbf + b*1024 + nq) = pb;          // local (L0 staging)
                sc_st8(H0m + b*512 + nq, pb);              // mirror (L1 staging)
            } else if (!L0 && ss >= 1){
                // ---- S4: h1 update + H2bf, tile n0 = lw*16 of 512
                const int t = ss - 1;
                const int n0 = lw*16, nq = n0 + kg*4;
                const int b = g16 + ln;
                f32x4 ppv = *(const f32x4*)(P3 + b*512 + nq);
                f32x4 zv  = *(const f32x4*)(z1 + b*512 + nq);
                f32x4 hpv = *(const f32x4*)(HHf + b*1024 + 512 + nq);
                f32x4 acc = mmT16<16,1024,512>(UhtT1 + n0*512, smem, ln, kg, zero);
                f32x4 bias = *(const f32x4*)(b1 + 1024 + nq);
                float hn[4];
                #pragma unroll
                for (int r = 0; r < 4; ++r){
                    float pre = acc[r] + ppv[r] + bias[r];
                    float ht = tanh_fast(pre);
                    hn[r] = (1.0f - zv[r])*hpv[r] + zv[r]*ht;
                }
                f32x4 hv = {hn[0], hn[1], hn[2], hn[3]};
                *(f32x4*)(HHf + b*1024 + 512 + nq) = hv;
                ull pb = pack4bf(hn);
                *(ull*)(HHbf + b*1024 + 512 + nq) = pb;    // local (L1 staging)
                *(ull*)(H2bf + (long long)(t*64 + b)*512 + nq) = pb;
            }
        }
        ++gen; gsyncp(flags, fidx, pbase, gen);
    }

    // h_final tail: each XCD writes its layer's 16 rows (local L2 reads).
    {
        const int l = L0 ? 0 : 1;
        const int c = lrank*512 + tid;           // 0..4095; need 2048
        if (c < 2048){
            const int b = g16 + (c >> 7), j4 = c & 127;
            f32x4 v = *(const f32x4*)(HHf + b*1024 + l*512 + j4*4);
            *(f32x4*)(outTail + l*32768 + b*512 + j4*4) = v;
        }
    }
}

// ---------------------------------------------------------------- launch ----
extern "C" void kernel_launch(void* const* d_in, const int* in_sizes, int n_in,
                              void* d_out, int out_size, void* d_ws, size_t ws_size,
                              hipStream_t stream)
{
    const int*   inputs = (const int*)d_in[0];
    const float* hidden = (const float*)d_in[1];
    const float* emb    = (const float*)d_in[2];
    const float* Wx     = (const float*)d_in[3];
    const float* Uh     = (const float*)d_in[4];
    const float* Uht    = (const float*)d_in[5];
    const float* b_rzh  = (const float*)d_in[6];
    const float* dec_w  = (const float*)d_in[7];
    const float* dec_b  = (const float*)d_in[8];
    float* out = (float*)d_out;

    char* w = (char*)d_ws;
    size_t off = 0;
    auto alloc = [&](size_t bytes)->char*{
        char* p = w + off; off = (off + bytes + 255) & ~(size_t)255; return p;
    };
    unsigned short* emb_bf = (unsigned short*)alloc(4096LL*512*2);
    unsigned short* WxT0   = (unsigned short*)alloc(1536LL*512*2);
    unsigned short* WX0    = (unsigned short*)alloc(4096LL*1536*2);
    unsigned short* UhT0   = (unsigned short*)alloc(1024LL*512*2);
    unsigned short* UhtT0  = (unsigned short*)alloc(512LL*512*2);
    unsigned short* Wx1T   = (unsigned short*)alloc(1536LL*512*2);
    unsigned short* Uh1T   = (unsigned short*)alloc(1024LL*512*2);
    unsigned short* UhtT1  = (unsigned short*)alloc(512LL*512*2);
    unsigned short* decpad = (unsigned short*)alloc(10112LL*512*2);
    float*          HH     = (float*)alloc(65536*4);
    unsigned short* HHbf   = (unsigned short*)alloc(65536*2);
    unsigned short* H0m    = (unsigned short*)alloc(64*512*2);
    unsigned short* rh0    = (unsigned short*)alloc(64*512*2);
    unsigned short* rh1    = (unsigned short*)alloc(64*512*2);
    float*          z0     = (float*)alloc(64*512*4);
    float*          z1     = (float*)alloc(64*512*4);
    float*          P3     = (float*)alloc(64*512*4);
    unsigned short* H2bf   = (unsigned short*)alloc(4096LL*512*2);
    unsigned int*   barzone= (unsigned int*)alloc(16384);
    if (off > ws_size) return;  // workspace too small: fail loudly via absmax

    prep_kernel<<<1024, 256, 0, stream>>>(inputs, hidden, emb, Wx, Uh, Uht, dec_w,
        emb_bf, WxT0, UhT0, UhtT0, Wx1T, Uh1T, UhtT1, decpad, HH, HHbf, H0m, barzone);

    // WX0 = embed @ Wx0  (M=4096, N=1536, K=512), bf16 out
    gemm128<<<dim3(32*12), 256, 0, stream>>>(emb_bf, WxT0, 4096, 1536, 512,
        0, nullptr, WX0, nullptr, 1536);

    // persistent recurrent kernel: 4 XCD-pairs, batch-split across pairs,
    // layer-split within pairs; all weights L2-resident
    gru_kernel<<<dim3(256), 512, 0, stream>>>(HH, HHbf, UhT0, UhtT0, Wx1T, Uh1T,
        UhtT1, WX0, rh0, rh1, z0, z1, P3, H2bf, H0m, b_rzh, out + 40960000, barzone);

    // decoder: logits = H2 @ dec_w^T + dec_b  (M=4096, N=10112 padded, K=512)
    gemm128<<<dim3(32*79), 256, 0, stream>>>(H2bf, decpad, 4096, 10112, 512,
        1, out, nullptr, dec_b, 10000);
}

// Round 15
// 1370.228 us; speedup vs baseline: 1.5677x; 1.0371x over previous
//
#include <hip/hip_runtime.h>
#include <hip/hip_bf16.h>

// GRU: SEQ=64, BATCH=64, HID=EMB=512, VOCAB=10000, LAYERS=2
// Outputs: logits (64,64,10000) f32 then h_final (2,64,512) f32, concat flat.
// R15 = R14 (4 XCD-pairs, batch-split across pairs, layer-split within pairs,
// weights L2-resident) + dependency-scoped barriers: bar1 intra-XCD; L0
// free-runs (4-deep H0m ring + throttle, R12-proven); L1 waits L0 at bar2.

#define SEQ 64
#define BPX 8      // worker blocks per XCD

typedef short s16x8 __attribute__((ext_vector_type(8)));   // 8 bf16 (4 VGPRs)
typedef float f32x4 __attribute__((ext_vector_type(4)));
typedef int   i32x4 __attribute__((ext_vector_type(4)));
typedef unsigned long long ull;

static __device__ __forceinline__ unsigned short f2bf(float f){
    unsigned int u = __float_as_uint(f);
    return (unsigned short)((u + 0x7FFFu + ((u >> 16) & 1u)) >> 16);  // RNE
}
static __device__ __forceinline__ float bf2f(unsigned short s){
    return __uint_as_float(((unsigned int)s) << 16);
}
static __device__ __forceinline__ float sigm(float x){
    return __fdividef(1.0f, 1.0f + __expf(-x));
}
static __device__ __forceinline__ float tanh_fast(float x){
    float ax = fabsf(x);
    float e = __expf(-2.0f * ax);
    float r = __fdividef(1.0f - e, 1.0f + e);
    return copysignf(r, x);
}
static __device__ __forceinline__ ull pack4bf(const float v[4]){
    union { ull u; unsigned short s[4]; } x;
    x.s[0]=f2bf(v[0]); x.s[1]=f2bf(v[1]); x.s[2]=f2bf(v[2]); x.s[3]=f2bf(v[3]);
    return x.u;
}
// sc0 sc1 = MALL-coherent cross-XCD path (R4/R6/R9-proven). Batched, one wait.
#define SC_LD16_NW(T,A) \
  asm volatile("global_load_dwordx4 %0, %1, off sc0 sc1" : "=&v"(T) : "v"(A) : "memory")
#define SC_WAIT() asm volatile("s_waitcnt vmcnt(0)" ::: "memory")
static __device__ __forceinline__ void sc_st8(void* p, ull v){
    asm volatile("global_store_dwordx2 %0, %1, off sc0 sc1" :: "v"(p), "v"(v) : "memory");
}

// ---------------------------------------------------------------- prep ------
__global__ void prep_kernel(const int* __restrict__ inputs, const float* __restrict__ hidden,
    const float* __restrict__ emb, const float* __restrict__ Wx, const float* __restrict__ Uh,
    const float* __restrict__ Uht, const float* __restrict__ dec_w,
    unsigned short* __restrict__ emb_bf, unsigned short* __restrict__ WxT0,
    unsigned short* __restrict__ UhT0, unsigned short* __restrict__ UhtT0,
    unsigned short* __restrict__ Wx1T, unsigned short* __restrict__ Uh1T,
    unsigned short* __restrict__ UhtT1, unsigned short* __restrict__ decpad,
    float* __restrict__ HH, unsigned short* __restrict__ HHbf,
    unsigned short* __restrict__ H0m, unsigned int* __restrict__ barzone)
{
    const long long stride = (long long)gridDim.x * blockDim.x;
    const long long t0 = (long long)blockIdx.x * blockDim.x + threadIdx.x;
    for (long long i = t0; i < 4096LL*512; i += stride){
        int r = (int)(i >> 9), k = (int)(i & 511);
        emb_bf[i] = f2bf(emb[(long long)inputs[r]*512 + k]);
    }
    for (long long i = t0; i < 1536LL*512; i += stride){
        int n = (int)(i >> 9), k = (int)(i & 511);
        WxT0[i] = f2bf(Wx[(long long)k*1536 + n]);
    }
    for (long long i = t0; i < 1024LL*512; i += stride){
        int n = (int)(i >> 9), k = (int)(i & 511);
        UhT0[i] = f2bf(Uh[(long long)k*1024 + n]);
    }
    for (long long i = t0; i < 512LL*512; i += stride){
        int n = (int)(i >> 9), k = (int)(i & 511);
        UhtT0[i] = f2bf(Uht[(long long)k*512 + n]);
    }
    for (long long i = t0; i < 1536LL*512; i += stride){
        int n = (int)(i >> 9), k = (int)(i & 511);
        Wx1T[i] = f2bf(Wx[(long long)(512 + k)*1536 + n]);     // Wx[1][k][n]
    }
    for (long long i = t0; i < 1024LL*512; i += stride){
        int n = (int)(i >> 9), k = (int)(i & 511);
        Uh1T[i] = f2bf(Uh[(long long)(512 + k)*1024 + n]);     // Uh[1][k][n]
    }
    for (long long i = t0; i < 512LL*512; i += stride){
        int n = (int)(i >> 9), k = (int)(i & 511);
        UhtT1[i] = f2bf(Uht[(long long)(512 + k)*512 + n]);
    }
    for (long long i = t0; i < 10112LL*512; i += stride){
        int n = (int)(i >> 9), k = (int)(i & 511);
        decpad[i] = (n < 10000) ? f2bf(dec_w[(long long)n*512 + k]) : (unsigned short)0;
    }
    for (long long i = t0; i < 65536; i += stride){
        int b = (int)(i >> 10), c = (int)(i & 1023);
        int l = c >> 9, j = c & 511;
        float v = hidden[((long long)l*64 + b)*512 + j];
        HH[i] = v; HHbf[i] = f2bf(v);                          // HH[b][l*512+j]
    }
    for (long long i = t0; i < 4LL*32768; i += stride){        // 4-ring h0 mirror
        int idx = (int)(i & 32767);
        int b = idx >> 9, j = idx & 511;
        H0m[i] = f2bf(hidden[(long long)b*512 + j]);
    }
    for (long long i = t0; i < 4096; i += stride) barzone[i] = 0u;
}

// ------------------------------------------------- tiled 128x128 bf16 GEMM --
__global__ __launch_bounds__(256) void gemm128(const unsigned short* __restrict__ A,
    const unsigned short* __restrict__ BT, int M, int N, int K, int mode,
    float* __restrict__ outF, unsigned short* __restrict__ outB,
    const float* __restrict__ bias, int Nreal)
{
    __shared__ unsigned short Ash[128*32];
    __shared__ unsigned short Bsh[128*32];
    const int nT = N >> 7;
    const int mb = blockIdx.x / nT, nb = blockIdx.x % nT;
    const int tid = threadIdx.x;
    const int lane = tid & 63, wId = tid >> 6;
    const int wm = wId >> 1, wn = wId & 1;
    const int ln = lane & 15, kg = lane >> 4;
    f32x4 acc[4][4];
    #pragma unroll
    for (int mt = 0; mt < 4; ++mt)
        #pragma unroll
        for (int nt = 0; nt < 4; ++nt) acc[mt][nt] = f32x4{0.f,0.f,0.f,0.f};

    for (int kc = 0; kc < K; kc += 32){
        #pragma unroll
        for (int it = 0; it < 2; ++it){
            int flat = it*256 + tid;
            int row = flat >> 2, kq = flat & 3;
            *(int4*)(&Ash[flat*8]) = *(const int4*)(A + (long long)(mb*128 + row)*K + kc + kq*8);
            *(int4*)(&Bsh[flat*8]) = *(const int4*)(BT + (long long)(nb*128 + row)*K + kc + kq*8);
        }
        __syncthreads();
        s16x8 af[4], bfv[4];
        #pragma unroll
        for (int mt = 0; mt < 4; ++mt) af[mt]  = *(const s16x8*)(&Ash[(wm*64 + mt*16 + ln)*32 + kg*8]);
        #pragma unroll
        for (int nt = 0; nt < 4; ++nt) bfv[nt] = *(const s16x8*)(&Bsh[(wn*64 + nt*16 + ln)*32 + kg*8]);
        #pragma unroll
        for (int mt = 0; mt < 4; ++mt)
            #pragma unroll
            for (int nt = 0; nt < 4; ++nt)
                acc[mt][nt] = __builtin_amdgcn_mfma_f32_16x16x32_bf16(af[mt], bfv[nt], acc[mt][nt], 0, 0, 0);
        __syncthreads();
    }
    #pragma unroll
    for (int mt = 0; mt < 4; ++mt)
        #pragma unroll
        for (int nt = 0; nt < 4; ++nt)
            #pragma unroll
            for (int r = 0; r < 4; ++r){
                int row = mb*128 + wm*64 + mt*16 + kg*4 + r;   // C/D: col=lane&15, row=(lane>>4)*4+reg
                int col = nb*128 + wn*64 + nt*16 + ln;
                float v = acc[mt][nt][r];
                if (mode == 0){
                    outB[(long long)row*N + col] = f2bf(v);
                } else {
                    if (col < Nreal) outF[(long long)row*Nreal + col] = v + bias[col];
                }
            }
}

// -------------------------------------------------------- persistent GRU ----
// Scoped barrier: store own flag (MALL sc0sc1, proven); poll own XCD's 8 flags
// at `gen`, plus optionally the partner XCD's 8 flags at `otherGen` (throttle /
// readiness). One poller lane per flag; bounded (hang-proof). buffer_inv ->
// plain cached loads see fresh local L2 (R7-proven).
static __device__ __forceinline__ void gsyncx(unsigned int* flags, int fidx, unsigned gen,
                                              int ownBase, int otherBase, int otherGen){
    SC_WAIT();
    __syncthreads();
    if (threadIdx.x < 64){
        if (threadIdx.x == 0){
            asm volatile("global_store_dword %0, %1, off sc0 sc1"
                         :: "v"(flags + fidx*32), "v"(gen) : "memory");
        }
        const int li = threadIdx.x;
        const unsigned int* p = flags;
        unsigned need = 0; bool active = false;
        if (li < BPX){ p = flags + (ownBase + li)*32; need = gen; active = true; }
        else if (li < 2*BPX && otherGen > 0){
            p = flags + (otherBase + (li - BPX))*32; need = (unsigned)otherGen; active = true;
        }
        unsigned v = need; int it = 0;
        do {
            if (active){
                asm volatile("global_load_dword %0, %1, off sc0 sc1\n\ts_waitcnt vmcnt(0)"
                             : "=v"(v) : "v"(p) : "memory");
            }
        } while (__ballot(v >= need) != ~0ull && ++it < (1 << 20));
    }
    __syncthreads();
    asm volatile("buffer_inv" ::: "memory");
}

// M=16 wave-tile with accumulate-in: D[16 n][16 b]. av = weight row (stride
// WSTRIDE elems, local-L2 cached); bv = LDS fragment (PITCH bytes/row, XOR swz).
// C/D: col(b)=lane&15, row(n)=(lane>>4)*4+reg.
template<int KIT, int PITCH, int WSTRIDE>
static __device__ __forceinline__ f32x4 mmT16(const unsigned short* __restrict__ W,
    const char* __restrict__ lds, int ln, int kg, f32x4 acc)
{
    #pragma unroll 4
    for (int k = 0; k < KIT; ++k){
        s16x8 bv = *(const s16x8*)(lds + ((ln*PITCH + k*64 + kg*16) ^ ((ln & 7) << 4)));
        s16x8 av = *(const s16x8*)(W + ln*WSTRIDE + k*32 + kg*8);
        acc = __builtin_amdgcn_mfma_f32_16x16x32_bf16(av, bv, acc, 0, 0, 0);
    }
    return acc;
}

__global__ __launch_bounds__(512, 1) void gru_kernel(
    float* __restrict__ HHf, unsigned short* __restrict__ HHbf,
    const unsigned short* __restrict__ UhT0, const unsigned short* __restrict__ UhtT0,
    const unsigned short* __restrict__ Wx1T, const unsigned short* __restrict__ Uh1T,
    const unsigned short* __restrict__ UhtT1,
    const unsigned short* __restrict__ WX0,
    unsigned short* __restrict__ rh0, unsigned short* __restrict__ rh1,
    float* __restrict__ z0, float* __restrict__ z1, float* __restrict__ P3,
    unsigned short* __restrict__ H2bf, unsigned short* __restrict__ H0m,
    const float* __restrict__ b_rzh,
    float* __restrict__ outTail, unsigned int* __restrict__ barzone)
{
    __shared__ __align__(16) char smem[32768];    // 16 rows x 2048 B
    __shared__ int s_xcc, s_lrank;
    const int tid = threadIdx.x, lane = tid & 63, wv = tid >> 6;  // 8 waves
    const int ln = lane & 15, kg = lane >> 4;

    // ---- direct XCD mapping: XCC_ID 0..7 (m09-verified); 8 workers each ----
    if (tid == 0){
        unsigned xcc;
        asm volatile("s_getreg_b32 %0, hwreg(HW_REG_XCC_ID)" : "=s"(xcc));
        xcc &= 7u;
        s_xcc = (int)xcc;
        s_lrank = (int)atomicAdd(barzone + 8 + xcc, 1u);
    }
    __syncthreads();
    const int lrank = s_lrank;
    if (lrank >= BPX) return;                    // spare blocks exit
    const int xcc = s_xcc;
    const int grp = xcc >> 1;                    // pair id 0..3
    const bool L0 = (xcc & 1) == 0;              // even XCD: layer 0
    const int g16 = grp * 16;                    // batch base
    const int lw = lrank*8 + wv;                 // XCD wave id 0..63
    const int fidx = xcc*8 + lrank;              // global flag index
    const int ownB = xcc*8, othB = (xcc ^ 1)*8;  // flag bases
    unsigned int* flags = barzone + 256;
    const float* b0 = b_rzh;
    const float* b1 = b_rzh + 1536;
    const f32x4 zero = {0.f, 0.f, 0.f, 0.f};
    unsigned gen = 0;

    for (int ss = 0; ss <= SEQ; ++ss){
        // ========== phase A: S1(ss)@L0-XCD || S3(ss-1)@L1-XCD ==============
        if (L0){
            // stage h0 (16 rows x 1024B, pitch 1024, swizzled), local
            const int4* src = (const int4*)HHbf;
            int4 t[2];
            #pragma unroll
            for (int j = 0; j < 2; ++j){
                const int c = tid + j*512, row = c >> 6, col = c & 63;
                t[j] = src[(g16 + row)*128 + col];
            }
            #pragma unroll
            for (int j = 0; j < 2; ++j){
                const int c = tid + j*512, row = c >> 6, col = c & 63;
                *(int4*)(smem + ((row*1024 + col*16) ^ ((row & 7) << 4))) = t[j];
            }
        } else {
            // stage h0 (ring mirror, sc) | h1 (local) -> 16 rows x 2048B pitch
            i32x4 tm[2]; int4 tl[2];
            const char* srcm = (const char*)(H0m + (long long)((ss + 3) & 3)*32768);
            const int4* srch = (const int4*)HHbf;
            #pragma unroll
            for (int j = 0; j < 2; ++j){
                const int c = tid + j*512, row = c >> 6, col = c & 63;
                SC_LD16_NW(tm[j], srcm + ((long long)(g16 + row)*64 + col)*16);
                tl[j] = srch[(g16 + row)*128 + 64 + col];
            }
            SC_WAIT();
            #pragma unroll
            for (int j = 0; j < 2; ++j){
                const int c = tid + j*512, row = c >> 6, col = c & 63;
                *(i32x4*)(smem + ((row*2048 + col*16) ^ ((row & 7) << 4))) = tm[j];
                *(int4*)(smem + ((row*2048 + 1024 + col*16) ^ ((row & 7) << 4))) = tl[j];
            }
        }
        __syncthreads();
        if (L0){
            if (ss < SEQ){
                // ---- S1: tile n0 = lw*16 of 1024, K=512
                const int n0 = lw*16, nq = n0 + kg*4;
                const int b = g16 + ln;
                union { ull u; unsigned short s[4]; } wx;
                wx.u = *(const ull*)(WX0 + (long long)(ss*64 + b)*1536 + nq);
                f32x4 acc = mmT16<16,1024,512>(UhT0 + n0*512, smem, ln, kg, zero);
                f32x4 bias = *(const f32x4*)(b0 + nq);
                float sg[4];
                #pragma unroll
                for (int r = 0; r < 4; ++r)
                    sg[r] = sigm(acc[r] + bf2f(wx.s[r]) + bias[r]);
                if (nq < 512){
                    union { ull u; unsigned short s[4]; } h;
                    h.u = *(const ull*)(smem + ((ln*1024 + nq*2) ^ ((ln & 7) << 4)));
                    float rv[4];
                    #pragma unroll
                    for (int r = 0; r < 4; ++r) rv[r] = sg[r] * bf2f(h.s[r]);
                    *(ull*)(rh0 + b*512 + nq) = pack4bf(rv);
                } else {
                    f32x4 zz = {sg[0], sg[1], sg[2], sg[3]};
                    *(f32x4*)(z0 + b*512 + (nq - 512)) = zz;
                }
            }
        } else {
            if (ss >= 1){
                // ---- S3: tile n0 = lw*16 of [0,1024): Wx1T(h0) + Uh1T(h1)
                const int n0 = lw*16, nq = n0 + kg*4;
                const int b = g16 + ln;
                f32x4 acc = mmT16<16,2048,512>(Wx1T + n0*512, smem, ln, kg, zero);
                acc = mmT16<16,2048,512>(Uh1T + n0*512, smem + 1024, ln, kg, acc);
                f32x4 bias = *(const f32x4*)(b1 + nq);
                if (nq < 512){
                    union { ull u; unsigned short s[4]; } h;
                    h.u = *(const ull*)(smem + ((ln*2048 + 1024 + nq*2) ^ ((ln & 7) << 4)));
                    float rv[4];
                    #pragma unroll
                    for (int r = 0; r < 4; ++r)
                        rv[r] = sigm(acc[r] + bias[r]) * bf2f(h.s[r]);
                    *(ull*)(rh1 + b*512 + nq) = pack4bf(rv);
                } else {
                    float sg[4];
                    #pragma unroll
                    for (int r = 0; r < 4; ++r)
                        sg[r] = sigm(acc[r] + bias[r]);
                    f32x4 zz = {sg[0], sg[1], sg[2], sg[3]};
                    *(f32x4*)(z1 + b*512 + (nq - 512)) = zz;
                }
                if (lw < 32){
                    // P3 tile: n0b in [1024,1536), h0 only (Uh half is zero)
                    const int n0b = 1024 + lw*16, nqb = n0b + kg*4;
                    f32x4 acc2 = mmT16<16,2048,512>(Wx1T + (long long)n0b*512, smem, ln, kg, zero);
                    *(f32x4*)(P3 + b*512 + (nqb - 1024)) = acc2;   // bias in S4
                }
            }
        }
        ++gen;   // bar1: intra-XCD; L0 additionally throttled to <=3 steps ahead
        if (L0) gsyncx(flags, fidx, gen, ownB, othB, (int)gen - 6);
        else    gsyncx(flags, fidx, gen, ownB, othB, 0);

        // ========== phase B: S2(ss)@L0-XCD || S4(ss-1)@L1-XCD ==============
        {
            // stage rh (16 rows x 1024B, pitch 1024, swizzled), local
            const int4* src = (const int4*)(L0 ? rh0 : rh1);
            int4 t[2];
            #pragma unroll
            for (int j = 0; j < 2; ++j){
                const int c = tid + j*512, row = c >> 6, col = c & 63;
                t[j] = src[(g16 + row)*64 + col];
            }
            #pragma unroll
            for (int j = 0; j < 2; ++j){
                const int c = tid + j*512, row = c >> 6, col = c & 63;
                *(int4*)(smem + ((row*1024 + col*16) ^ ((row & 7) << 4))) = t[j];
            }
        }
        __syncthreads();
        if (lw < 32){
            if (L0 && ss < SEQ){
                // ---- S2: h0 update, tile n0 = lw*16 of 512
                const int n0 = lw*16, nq = n0 + kg*4;
                const int b = g16 + ln;
                union { ull u; unsigned short s[4]; } wx;
                wx.u = *(const ull*)(WX0 + (long long)(ss*64 + b)*1536 + 1024 + nq);
                f32x4 zv  = *(const f32x4*)(z0 + b*512 + nq);
                f32x4 hpv = *(const f32x4*)(HHf + b*1024 + nq);
                f32x4 acc = mmT16<16,1024,512>(UhtT0 + n0*512, smem, ln, kg, zero);
                f32x4 bias = *(const f32x4*)(b0 + 1024 + nq);
                float hn[4];
                #pragma unroll
                for (int r = 0; r < 4; ++r){
                    float pre = acc[r] + bf2f(wx.s[r]) + bias[r];
                    float ht = tanh_fast(pre);
                    hn[r] = (1.0f - zv[r])*hpv[r] + zv[r]*ht;
                }
                f32x4 hv = {hn[0], hn[1], hn[2], hn[3]};
                *(f32x4*)(HHf + b*1024 + nq) = hv;
                ull pb = pack4bf(hn);
                *(ull*)(HHbf + b*1024 + nq) = pb;          // local (L0 staging)
                sc_st8(H0m + (long long)(ss & 3)*32768 + b*512 + nq, pb);  // ring mirror
            } else if (!L0 && ss >= 1){
                // ---- S4: h1 update + H2bf, tile n0 = lw*16 of 512
                const int t = ss - 1;
                const int n0 = lw*16, nq = n0 + kg*4;
                const int b = g16 + ln;
                f32x4 ppv = *(const f32x4*)(P3 + b*512 + nq);
                f32x4 zv  = *(const f32x4*)(z1 + b*512 + nq);
                f32x4 hpv = *(const f32x4*)(HHf + b*1024 + 512 + nq);
                f32x4 acc = mmT16<16,1024,512>(UhtT1 + n0*512, smem, ln, kg, zero);
                f32x4 bias = *(const f32x4*)(b1 + 1024 + nq);
                float hn[4];
                #pragma unroll
                for (int r = 0; r < 4; ++r){
                    float pre = acc[r] + ppv[r] + bias[r];
                    float ht = tanh_fast(pre);
                    hn[r] = (1.0f - zv[r])*hpv[r] + zv[r]*ht;
                }
                f32x4 hv = {hn[0], hn[1], hn[2], hn[3]};
                *(f32x4*)(HHf + b*1024 + 512 + nq) = hv;
                ull pb = pack4bf(hn);
                *(ull*)(HHbf + b*1024 + 512 + nq) = pb;    // local (L1 staging)
                *(ull*)(H2bf + (long long)(t*64 + b)*512 + nq) = pb;
            }
        }
        ++gen;   // bar2: L0 waits own XCD only; L1 waits own + L0 (ring ready)
        if (L0) gsyncx(flags, fidx, gen, ownB, othB, 0);
        else    gsyncx(flags, fidx, gen, ownB, othB, (int)gen);
    }

    // h_final tail: each XCD writes its layer's 16 rows (local L2 reads).
    {
        const int l = L0 ? 0 : 1;
        const int c = lrank*512 + tid;           // 0..4095; need 2048
        if (c < 2048){
            const int b = g16 + (c >> 7), j4 = c & 127;
            f32x4 v = *(const f32x4*)(HHf + b*1024 + l*512 + j4*4);
            *(f32x4*)(outTail + l*32768 + b*512 + j4*4) = v;
        }
    }
}

// ---------------------------------------------------------------- launch ----
extern "C" void kernel_launch(void* const* d_in, const int* in_sizes, int n_in,
                              void* d_out, int out_size, void* d_ws, size_t ws_size,
                              hipStream_t stream)
{
    const int*   inputs = (const int*)d_in[0];
    const float* hidden = (const float*)d_in[1];
    const float* emb    = (const float*)d_in[2];
    const float* Wx     = (const float*)d_in[3];
    const float* Uh     = (const float*)d_in[4];
    const float* Uht    = (const float*)d_in[5];
    const float* b_rzh  = (const float*)d_in[6];
    const float* dec_w  = (const float*)d_in[7];
    const float* dec_b  = (const float*)d_in[8];
    float* out = (float*)d_out;

    char* w = (char*)d_ws;
    size_t off = 0;
    auto alloc = [&](size_t bytes)->char*{
        char* p = w + off; off = (off + bytes + 255) & ~(size_t)255; return p;
    };
    unsigned short* emb_bf = (unsigned short*)alloc(4096LL*512*2);
    unsigned short* WxT0   = (unsigned short*)alloc(1536LL*512*2);
    unsigned short* WX0    = (unsigned short*)alloc(4096LL*1536*2);
    unsigned short* UhT0   = (unsigned short*)alloc(1024LL*512*2);
    unsigned short* UhtT0  = (unsigned short*)alloc(512LL*512*2);
    unsigned short* Wx1T   = (unsigned short*)alloc(1536LL*512*2);
    unsigned short* Uh1T   = (unsigned short*)alloc(1024LL*512*2);
    unsigned short* UhtT1  = (unsigned short*)alloc(512LL*512*2);
    unsigned short* decpad = (unsigned short*)alloc(10112LL*512*2);
    float*          HH     = (float*)alloc(65536*4);
    unsigned short* HHbf   = (unsigned short*)alloc(65536*2);
    unsigned short* H0m    = (unsigned short*)alloc(4LL*32768*2);   // 4-ring mirror
    unsigned short* rh0    = (unsigned short*)alloc(64*512*2);
    unsigned short* rh1    = (unsigned short*)alloc(64*512*2);
    float*          z0     = (float*)alloc(64*512*4);
    float*          z1     = (float*)alloc(64*512*4);
    float*          P3     = (float*)alloc(64*512*4);
    unsigned short* H2bf   = (unsigned short*)alloc(4096LL*512*2);
    unsigned int*   barzone= (unsigned int*)alloc(16384);
    if (off > ws_size) return;  // workspace too small: fail loudly via absmax

    prep_kernel<<<1024, 256, 0, stream>>>(inputs, hidden, emb, Wx, Uh, Uht, dec_w,
        emb_bf, WxT0, UhT0, UhtT0, Wx1T, Uh1T, UhtT1, decpad, HH, HHbf, H0m, barzone);

    // WX0 = embed @ Wx0  (M=4096, N=1536, K=512), bf16 out
    gemm128<<<dim3(32*12), 256, 0, stream>>>(emb_bf, WxT0, 4096, 1536, 512,
        0, nullptr, WX0, nullptr, 1536);

    // persistent recurrent kernel: 4 XCD-pairs, scoped barriers, L0 free-run
    gru_kernel<<<dim3(256), 512, 0, stream>>>(HH, HHbf, UhT0, UhtT0, Wx1T, Uh1T,
        UhtT1, WX0, rh0, rh1, z0, z1, P3, H2bf, H0m, b_rzh, out + 40960000, barzone);

    // decoder: logits = H2 @ dec_w^T + dec_b  (M=4096, N=10112 padded, K=512)
    gemm128<<<dim3(32*79), 256, 0, stream>>>(H2bf, decpad, 4096, 10112, 512,
        1, out, nullptr, dec_b, 10000);
}